// Round 27
// baseline (467.015 us; speedup 1.0000x reference)
//
#include <hip/hip_runtime.h>
#include <math.h>

namespace {
constexpr int BB = 4096;   // batch
constexpr int NN = 41;     // nodes
constexpr int DD = 271;    // features
constexpr int DP = 288;    // padded feature dim (multiple of 32)
constexpr int PW = 44;     // padded row stride for 41-wide LDS matrices
constexpr long long MROWS = (long long)BB * NN;   // 167936
constexpr int WBE = DP * DP * 2;     // per-weight split Bint stride (ushorts)
constexpr int WBS = (DP / 32) * DP * 32;  // per-weight single Bsng stride (ushorts)
constexpr int SROW = 312;            // fused-kernel S row stride (ushorts)
constexpr int NPL = 5;               // Y planes of 64 k (K padded to 320)
constexpr int MSZ = NN * PW * 4;     // one f32 matrix = 7216 B (16B-aligned)
}

typedef __attribute__((ext_vector_type(8)))  unsigned short ushort8;
typedef __attribute__((ext_vector_type(8)))  short          short8;
typedef __attribute__((ext_vector_type(4)))  float          f32x4;

__device__ __forceinline__ unsigned short f2bf(float f) {
    unsigned u = __float_as_uint(f);
    unsigned r = (u + 0x7FFFu + ((u >> 16) & 1u)) >> 16;
    return (unsigned short)r;
}
__device__ __forceinline__ float bf2f(unsigned short h) {
    return __uint_as_float(((unsigned)h) << 16);
}

// ---------------------------------------------------------------------------
// split k-major layout (W2, MPint): element (row, k) of a plane with
// `nrows` rows at ((k>>5)*nrows + row)*64 + chunk^(row&7); hi 0..3, lo 4..7.
// ---------------------------------------------------------------------------
__device__ __forceinline__ void store_split_km(unsigned short* __restrict__ dst,
                                               long long nrows, long long row,
                                               int col, float v)
{
    const unsigned short hh = f2bf(v);
    const unsigned short ll = f2bf(v - bf2f(hh));
    const long long base = ((long long)(col >> 5) * nrows + row) * 64;
    const int cn = (col & 31) >> 3, k7 = col & 7, sw = (int)(row & 7);
    dst[base + ((cn ^ sw) << 3) + k7]       = hh;
    dst[base + (((cn + 4) ^ sw) << 3) + k7] = ll;
}

// ---------------------------------------------------------------------------
// LDS matmul helper: C = scale * A@B - (sub ? sub : 0), 41x41, stride-44 rows.
// ---------------------------------------------------------------------------
__device__ __forceinline__ void lds_mm(const float (*__restrict__ A)[PW],
                                       const float (*__restrict__ B)[PW],
                                       float (*__restrict__ C)[PW],
                                       const float scale,
                                       const float (*__restrict__ sub)[PW],
                                       const int tid)
{
    for (int s = tid; s < NN * 11; s += 256) {
        const int i = s / 11, q = s % 11;
        float4 acc = make_float4(0.f, 0.f, 0.f, 0.f);
        #pragma unroll
        for (int k = 0; k < NN; ++k) {
            const float a = A[i][k];
            const float4 b4 = *reinterpret_cast<const float4*>(&B[k][q * 4]);
            acc.x = fmaf(a, b4.x, acc.x); acc.y = fmaf(a, b4.y, acc.y);
            acc.z = fmaf(a, b4.z, acc.z); acc.w = fmaf(a, b4.w, acc.w);
        }
        float4 r;
        if (sub) {
            const float4 s4 = *reinterpret_cast<const float4*>(&sub[i][q * 4]);
            r = make_float4(fmaf(scale, acc.x, -s4.x), fmaf(scale, acc.y, -s4.y),
                            fmaf(scale, acc.z, -s4.z), fmaf(scale, acc.w, -s4.w));
        } else {
            r = make_float4(scale * acc.x, scale * acc.y, scale * acc.z, scale * acc.w);
        }
        *reinterpret_cast<float4*>(&C[i][q * 4]) = r;
    }
}

// ---------------------------------------------------------------------------
// K1+K2 MERGED (k_wav): per sample, one 256-thread block.
// Phase A: wavelet basis -> M = l1n(thr(W)) @ diag(gk) @ l1n(thr(Wi)),
//          parked as bf16 in dedicated sMm (zero-padded [48][68]).
// Phase B: Y = M @ X via MFMA (proven k_wavX body); the five f32 matrices
//          are OVERLAID by sXT/sYb in a 63.4 KB union (barrier-separated).
// No MT global round-trip. LDS ~70.5 KB -> 2 blocks/CU.
// ---------------------------------------------------------------------------
__global__ __launch_bounds__(256, 2) void k_wav(const float* __restrict__ G,
                                                const float* __restrict__ gk,
                                                const float* __restrict__ X,
                                                unsigned short* __restrict__ Yint)
{
    constexpr int XJ  = 68;                    // j-stride (136B rows)
    constexpr int YST = 296;                   // sYb col stride
    __shared__ __align__(16) char um[288 * XJ * 2 + NN * YST * 2];  // 63440 B
    __shared__ __align__(16) unsigned short sMm[48 * XJ];           //  6528 B
    __shared__ float sdeg[NN], sdinv[NN], srs[NN];
    __shared__ float slam16;

    float (*sG)[PW]  = reinterpret_cast<float(*)[PW]>(um + 0 * MSZ);
    float (*sL)[PW]  = reinterpret_cast<float(*)[PW]>(um + 1 * MSZ);
    float (*sT2)[PW] = reinterpret_cast<float(*)[PW]>(um + 2 * MSZ);
    float (*sT3)[PW] = reinterpret_cast<float(*)[PW]>(um + 3 * MSZ);
    float (*sM)[PW]  = reinterpret_cast<float(*)[PW]>(um + 4 * MSZ);

    const int b   = blockIdx.x;
    const int tid = threadIdx.x;
    const float* Gb = G + (size_t)b * NN * NN;

    // zero sMm (pads must be 0) while staging G
    {
        const ushort8 z8 = {0, 0, 0, 0, 0, 0, 0, 0};
        for (int e = tid; e < (48 * XJ) / 8; e += 256)
            *reinterpret_cast<ushort8*>(&sMm[e * 8]) = z8;
    }
    for (int e = tid; e < NN * PW; e += 256) {
        const int i = e / PW, j = e % PW;
        sG[i][j] = (j < NN) ? Gb[i * NN + j] : 0.0f;
    }
    __syncthreads();

    if (tid < NN) {
        float4 s4 = make_float4(0.f, 0.f, 0.f, 0.f);
        #pragma unroll
        for (int q = 0; q < 11; ++q) {
            const float4 g4 = *reinterpret_cast<const float4*>(&sG[tid][q * 4]);
            s4.x += g4.x; s4.y += g4.y; s4.z += g4.z; s4.w += g4.w;
        }
        const float s = (s4.x + s4.y) + (s4.z + s4.w);
        sdeg[tid]  = s;
        sdinv[tid] = 1.0f / (sqrtf(s) + 1e-6f);
    }
    __syncthreads();

    for (int e = tid; e < NN * PW; e += 256) {
        const int i = e / PW, j = e % PW;
        if (j < NN) {
            const float a = 0.5f * (sG[i][j] + sG[j][i]);
            const float v = ((i == j) ? sdeg[i] : 0.0f) - a;
            sL[i][j] = sdinv[i] * sdinv[j] * v;
        } else {
            sL[i][j] = 0.0f;
        }
    }
    __syncthreads();

    lds_mm(sL, sL, sT2, 2.0f, nullptr, tid);   // T2 = 2 L^2
    __syncthreads();
    lds_mm(sL, sT2, sT3, 2.0f, sL, tid);       // T3 = 2 L T2 - L
    __syncthreads();

    lds_mm(sT2, sT2, sM, 0.25f, nullptr, tid); // L^4
    __syncthreads();
    lds_mm(sM, sM, sG, 1.0f, nullptr, tid);    // L^8  -> sG
    __syncthreads();
    lds_mm(sG, sG, sM, 1.0f, nullptr, tid);    // L^16 -> sM
    __syncthreads();

    if (tid < 64) {
        float lr[NN];
        #pragma unroll
        for (int j = 0; j < NN; ++j) lr[j] = (tid < NN) ? sM[tid][j] : 0.0f;
        unsigned h = (unsigned)(tid + 1) * 2654435761u;
        h ^= h >> 13; h *= 0x85ebca6bu; h ^= h >> 16;
        float v = (tid < NN) ? (0.25f + (float)(h & 1023) * (1.0f / 1024.0f)) : 0.0f;
        float n2 = v * v;
        #pragma unroll
        for (int off = 32; off > 0; off >>= 1) n2 += __shfl_xor(n2, off, 64);
        v *= rsqrtf(n2);
        float lam = 1.0f;
        #pragma unroll
        for (int it = 0; it < 4; ++it) {
            float acc = 0.f;
            #pragma unroll
            for (int j = 0; j < NN; ++j) acc = fmaf(lr[j], __shfl(v, j, 64), acc);
            float m2 = acc * acc;
            #pragma unroll
            for (int off = 32; off > 0; off >>= 1) m2 += __shfl_xor(m2, off, 64);
            lam = sqrtf(m2);
            v = acc * (1.0f / lam);
        }
        if (tid == 0) slam16 = lam;
    }
    __syncthreads();

    const float x = 0.15f * exp2f(log2f(slam16) * (1.0f / 16.0f));
    float iv[4];
    {
        const float xh = 0.5f * x, xh2 = xh * xh;
        #pragma unroll
        for (int n = 0; n < 4; ++n) {
            float c = 1.0f;
            for (int q = 2; q <= n; ++q) c /= (float)q;
            float p = 1.0f;
            for (int q = 0; q < n; ++q) p *= xh;
            float s = 0.f;
            for (int k = 0; k < 25; ++k) {
                s += c * p;
                p *= xh2;
                c /= (float)((k + 1) * (k + 1 + n));
            }
            iv[n] = s;
        }
    }
    const float ex = expf(x), emx = expf(-x);

    // Wn = l1norm(thresh(W)) -> sM
    {
        const float a1 = 2.f * ex * iv[1], a2 = 2.f * ex * iv[2], a3 = 2.f * ex * iv[3];
        for (int s = tid; s < NN * 11; s += 256) {
            const int i = s / 11, q = s % 11;
            const float4 l4  = *reinterpret_cast<const float4*>(&sL[i][q * 4]);
            const float4 t24 = *reinterpret_cast<const float4*>(&sT2[i][q * 4]);
            const float4 t34 = *reinterpret_cast<const float4*>(&sT3[i][q * 4]);
            float4 w;
            w.x = fmaf(a1, l4.x, fmaf(a2, t24.x, a3 * t34.x));
            w.y = fmaf(a1, l4.y, fmaf(a2, t24.y, a3 * t34.y));
            w.z = fmaf(a1, l4.z, fmaf(a2, t24.z, a3 * t34.z));
            w.w = fmaf(a1, l4.w, fmaf(a2, t24.w, a3 * t34.w));
            w.x = (w.x < 1e-4f) ? 0.f : w.x;  w.y = (w.y < 1e-4f) ? 0.f : w.y;
            w.z = (w.z < 1e-4f) ? 0.f : w.z;  w.w = (w.w < 1e-4f) ? 0.f : w.w;
            *reinterpret_cast<float4*>(&sM[i][q * 4]) = w;
        }
        __syncthreads();
        if (tid < NN) {
            float s = 0.f;
            #pragma unroll
            for (int q = 0; q < 11; ++q) {
                const float4 w4 = *reinterpret_cast<const float4*>(&sM[tid][q * 4]);
                s += fabsf(w4.x) + fabsf(w4.y) + fabsf(w4.z) + fabsf(w4.w);
            }
            srs[tid] = 1.0f / fmaxf(s, 1e-12f);
        }
        __syncthreads();
    }
    // scale Wn rows; Win = thresh(Wi) -> sG
    {
        const float a1 = -2.f * emx * iv[1], a2 = 2.f * emx * iv[2], a3 = -2.f * emx * iv[3];
        for (int s = tid; s < NN * 11; s += 256) {
            const int i = s / 11, q = s % 11;
            float4 m4 = *reinterpret_cast<float4*>(&sM[i][q * 4]);
            const float rs = srs[i];
            m4.x *= rs; m4.y *= rs; m4.z *= rs; m4.w *= rs;
            *reinterpret_cast<float4*>(&sM[i][q * 4]) = m4;
            const float4 l4  = *reinterpret_cast<const float4*>(&sL[i][q * 4]);
            const float4 t24 = *reinterpret_cast<const float4*>(&sT2[i][q * 4]);
            const float4 t34 = *reinterpret_cast<const float4*>(&sT3[i][q * 4]);
            float4 w;
            w.x = fmaf(a1, l4.x, fmaf(a2, t24.x, a3 * t34.x));
            w.y = fmaf(a1, l4.y, fmaf(a2, t24.y, a3 * t34.y));
            w.z = fmaf(a1, l4.z, fmaf(a2, t24.z, a3 * t34.z));
            w.w = fmaf(a1, l4.w, fmaf(a2, t24.w, a3 * t34.w));
            w.x = (w.x < 1e-4f) ? 0.f : w.x;  w.y = (w.y < 1e-4f) ? 0.f : w.y;
            w.z = (w.z < 1e-4f) ? 0.f : w.z;  w.w = (w.w < 1e-4f) ? 0.f : w.w;
            *reinterpret_cast<float4*>(&sG[i][q * 4]) = w;
        }
        __syncthreads();
        if (tid < NN) {
            float s = 0.f;
            #pragma unroll
            for (int q = 0; q < 11; ++q) {
                const float4 w4 = *reinterpret_cast<const float4*>(&sG[tid][q * 4]);
                s += fabsf(w4.x) + fabsf(w4.y) + fabsf(w4.z) + fabsf(w4.w);
            }
            sdeg[tid] = gk[tid] / fmaxf(s, 1e-12f);
        }
        __syncthreads();
        for (int s = tid; s < NN * 11; s += 256) {
            const int j = s / 11, q = s % 11;
            float4 w4 = *reinterpret_cast<float4*>(&sG[j][q * 4]);
            const float rs = sdeg[j];
            w4.x *= rs; w4.y *= rs; w4.z *= rs; w4.w *= rs;
            *reinterpret_cast<float4*>(&sG[j][q * 4]) = w4;
        }
        __syncthreads();
    }
    lds_mm(sM, sG, sL, 1.0f, nullptr, tid);   // M = Wn @ diag(gk) Win -> sL
    __syncthreads();

    // park M as bf16 in sMm (pads already zero)
    for (int e = tid; e < NN * NN; e += 256) {
        const int i = e / NN, j = e % NN;
        sMm[i * XJ + j] = f2bf(sL[i][j]);
    }
    __syncthreads();   // last read of the f32 matrices; union is now free

    // ---------------- phase B: Y = M @ X via MFMA ----------------
    unsigned short* sXT = reinterpret_cast<unsigned short*>(um);            // 288*68
    unsigned short* sYb = reinterpret_cast<unsigned short*>(um + 288 * XJ * 2); // 41*296
    const int lane = tid & 63, w = tid >> 6;
    const int lr = lane & 15;
    const int hi8 = (lane >> 4) * 8;

    {
        const ushort8 z8 = {0, 0, 0, 0, 0, 0, 0, 0};
        for (int e = tid; e < (288 * XJ) / 8; e += 256)
            *reinterpret_cast<ushort8*>(&sXT[e * 8]) = z8;
    }
    __syncthreads();

    const float* __restrict__ Xb = X + (size_t)b * NN * DD;
    for (int e = tid; e < NN * DD; e += 256) {
        const int j = e / DD, c = e % DD;
        sXT[c * XJ + j] = f2bf(Xb[e]);
    }
    __syncthreads();

    for (int t = w; t < 54; t += 4) {
        const int mt = t / 18, nt = t % 18;
        f32x4 acc = (f32x4){0.f, 0.f, 0.f, 0.f};
        #pragma unroll
        for (int ks = 0; ks < 2; ++ks) {
            const short8 a = *reinterpret_cast<const short8*>(
                &sMm[(mt * 16 + lr) * XJ + ks * 32 + hi8]);
            const short8 bf = *reinterpret_cast<const short8*>(
                &sXT[(nt * 16 + lr) * XJ + ks * 32 + hi8]);
            acc = __builtin_amdgcn_mfma_f32_16x16x32_bf16(a, bf, acc, 0, 0, 0);
        }
        const int row0 = mt * 16 + (lane >> 4) * 4;
        const int col  = nt * 16 + lr;
        #pragma unroll
        for (int rr = 0; rr < 4; ++rr) {
            const int row = row0 + rr;
            if (row < NN) sYb[row * YST + col] = f2bf(acc[rr]);
        }
    }
    __syncthreads();

    // repack to Yint plane layout with 16B stores
    for (int t = tid; t < NN * 36; t += 256) {
        const int i = t / 36, c8 = t % 36;
        const ushort8 hv = *reinterpret_cast<const ushort8*>(&sYb[i * YST + c8 * 8]);
        const long long r = (long long)b * NN + i;
        const int p = c8 >> 3;                           // plane (64k)
        const int chunk = ((c8 >> 2) & 1) * 4 + (c8 & 3);
        const int sw = (int)(r & 7);
        unsigned short* base = Yint + ((long long)p * MROWS + r) * 64;
        *reinterpret_cast<ushort8*>(base + ((chunk ^ sw) << 3)) = hv;
    }
}

// ---------------------------------------------------------------------------
// Prep: weights -> split k-major Bint (W2 for gemm3) AND single-bf16
// k-major Bsng (gW, W1 for the fused kernel). Also coff = exp(lsv).
// ---------------------------------------------------------------------------
__global__ __launch_bounds__(256) void k_splitB(const float* __restrict__ gW,
                                                const float* __restrict__ W1,
                                                const float* __restrict__ W2,
                                                const float* __restrict__ lsv,
                                                unsigned short* __restrict__ Bint,
                                                unsigned short* __restrict__ Bsng,
                                                float* __restrict__ coff)
{
    const int t = blockIdx.x * 256 + threadIdx.x;
    if (t < NN * DD) coff[t] = expf(lsv[t]);
    if (t >= 3 * DP * DP) return;
    const int w = t / (DP * DP);
    const int r = t % (DP * DP);
    const int n = r / DP, k = r % DP;
    const float* src = (w == 0) ? gW : ((w == 1) ? W1 : W2);
    const float v = (n < DD && k < DD) ? src[k * DD + n] : 0.0f;
    store_split_km(Bint + (size_t)w * WBE, DP, n, k, v);
    if (w < 2) {
        Bsng[(size_t)w * WBS + ((long long)(k >> 5) * DP + n) * 32 +
             (((k & 31) >> 3) << 3) + (k & 7)] = f2bf(v);
    }
}

// ---------------------------------------------------------------------------
__device__ __forceinline__ void async16(const unsigned short* __restrict__ g,
                                        unsigned short* l)
{
    __builtin_amdgcn_global_load_lds(
        (const __attribute__((address_space(1))) unsigned int*)g,
        (__attribute__((address_space(3))) unsigned int*)l, 16, 0, 0);
}

// ---------------------------------------------------------------------------
// K3 v11: FUSED GEMM1+GEMM2+NODE-MEAN, atomic-free hot path (r26 winner).
// ---------------------------------------------------------------------------
__global__ __launch_bounds__(512, 2) void k_fused(
    const unsigned short* __restrict__ Aint,   // Y, single k-major planes
    const unsigned short* __restrict__ Bs0,    // gW single k-major
    const unsigned short* __restrict__ Bs1,    // W1 single k-major
    const float* __restrict__ coff,
    const float* __restrict__ b1,
    float* __restrict__ seqsum)                // [BB][DP] f32, pre-zeroed
{
    __shared__ __align__(16) unsigned short sS[256 * SROW];     // 156 KB
    const int tid  = threadIdx.x;
    const int lane = tid & 63, w = tid >> 6;    // 8 waves
    const int wr = w >> 1, wc = w & 1;          // wr 0..3 (64-row groups)
    const int lr = lane & 15, cb = lane >> 4;
    const int sw = lr & 7;

    const int nwg = gridDim.x, orig = blockIdx.x;
    const int q = nwg >> 3, r = nwg & 7;
    const int xcd = orig & 7, loc = orig >> 3;
    const int bid = (xcd < r ? xcd * (q + 1) : r * (q + 1) + (xcd - r) * q) + loc;
    const long long row0 = (long long)bid * 256;

    const unsigned short* __restrict__ b0p = Bs0 + (size_t)(wc * 144 + lr) * 32 + cb * 8;
    const unsigned short* __restrict__ b1p = Bs1 + (size_t)(wc * 144 + lr) * 32 + cb * 8;

    f32x4 acc[4][9];
    #pragma unroll
    for (int mf = 0; mf < 4; ++mf)
        #pragma unroll
        for (int nf = 0; nf < 9; ++nf)
            acc[mf][nf] = (f32x4){0.f, 0.f, 0.f, 0.f};

    // ---------------- phase 1: acc = Y @ gW  (NO barriers) ----------------
    for (int t = 0; t < 9; ++t) {
        const int p  = t >> 1;
        const int hc = (t & 1) * 4 + cb;
        const long long abase = ((long long)p * MROWS + row0) * 64 + ((hc ^ sw) << 3);
        short8 a[4];
        #pragma unroll
        for (int mf = 0; mf < 4; ++mf)
            a[mf] = *reinterpret_cast<const short8*>(
                Aint + abase + (long long)(wr * 64 + mf * 16 + lr) * 64);
        const long long toff = (long long)t * DP * 32;
        #pragma unroll
        for (int nf = 0; nf < 9; ++nf) {
            const short8 bh = *reinterpret_cast<const short8*>(b0p + toff + (long long)nf * 512);
            #pragma unroll
            for (int mf = 0; mf < 4; ++mf)
                acc[mf][nf] = __builtin_amdgcn_mfma_f32_16x16x32_bf16(a[mf], bh, acc[mf][nf], 0, 0, 0);
        }
    }

    // epilogue 1: S = coff*relu(acc) -> sS (pad cols get coff 0 -> S=0)
    #pragma unroll
    for (int mf = 0; mf < 4; ++mf) {
        const int mb = wr * 64 + mf * 16 + ((lane >> 4) * 4);
        #pragma unroll
        for (int nf = 0; nf < 9; ++nf) {
            const int col = wc * 144 + nf * 16 + lr;
            #pragma unroll
            for (int rr = 0; rr < 4; ++rr) {
                const int m = mb + rr;
                float v = fmaxf(acc[mf][nf][rr], 0.f);
                const float cf = (col < DD) ? coff[((unsigned)(row0 + m) % 41u) * DD + col] : 0.0f;
                sS[m * SROW + col] = f2bf(v * cf);
                acc[mf][nf][rr] = 0.f;
            }
        }
    }
    __syncthreads();   // S complete before cross-wave reads

    // ---------------- phase 2: acc = S @ W1 (single A from LDS, single B) --
    for (int t = 0; t < 9; ++t) {
        short8 ah[4];
        #pragma unroll
        for (int mf = 0; mf < 4; ++mf) {
            const int m = wr * 64 + mf * 16 + lr;
            ah[mf] = *reinterpret_cast<const short8*>(&sS[m * SROW + t * 32 + cb * 8]);
        }
        const long long toff = (long long)t * DP * 32;
        #pragma unroll
        for (int nf = 0; nf < 9; ++nf) {
            const short8 bh = *reinterpret_cast<const short8*>(b1p + toff + (long long)nf * 512);
            #pragma unroll
            for (int mf = 0; mf < 4; ++mf)
                acc[mf][nf] = __builtin_amdgcn_mfma_f32_16x16x32_bf16(ah[mf], bh, acc[mf][nf], 0, 0, 0);
        }
    }
    __syncthreads();   // all phase-2 sS reads complete before overwrite

    // epilogue 2a: P2 values (bf16) -> sS, own rows only (no hazards)
    #pragma unroll
    for (int mf = 0; mf < 4; ++mf) {
        const int mb = wr * 64 + mf * 16 + ((lane >> 4) * 4);
        #pragma unroll
        for (int nf = 0; nf < 9; ++nf) {
            const int col = wc * 144 + nf * 16 + lr;
            const float bv = (col < DD) ? b1[col] : 0.0f;
            #pragma unroll
            for (int rr = 0; rr < 4; ++rr) {
                const float v = fmaxf(acc[mf][nf][rr] + bv, 0.f);
                sS[(mb + rr) * SROW + col] = f2bf(v);
            }
        }
    }
    __syncthreads();

    // epilogue 2b: cooperative node-sum, then one global atomicAdd each
    const long long b0 = row0 / 41;
    for (int e = tid; e < 8 * DP; e += 512) {
        const int ls = e / DP, col = e % DP;
        const long long bsm = b0 + ls;
        if (bsm >= BB) continue;
        const long long gr0 = bsm * 41, gr1 = gr0 + 41;
        const int m0 = (int)((gr0 > row0 ? gr0 : row0) - row0);
        const long long hi = (gr1 < row0 + 256 ? gr1 : row0 + 256);
        const int m1 = (int)(hi - row0);
        if (m0 >= m1) continue;
        float s = 0.f;
        for (int m = m0; m < m1; ++m) s += bf2f(sS[m * SROW + col]);
        atomicAdd(&seqsum[bsm * DP + col], s);
    }
}

// ---------------------------------------------------------------------------
// K5: seqsum/41 -> split k-major MPint (BB rows).
// ---------------------------------------------------------------------------
__global__ __launch_bounds__(320) void k_mp(const float* __restrict__ seqsum,
                                            unsigned short* __restrict__ MPint)
{
    const int b = blockIdx.x;
    const int c = threadIdx.x;
    if (c >= DP) return;
    store_split_km(MPint, BB, b, c, seqsum[(size_t)b * DP + c] * (1.0f / 41.0f));
}

// ---------------------------------------------------------------------------
// K6: GEMM3 (small): seq = mean @ W2 + b2 (split path, unchanged).
// ---------------------------------------------------------------------------
__global__ __launch_bounds__(256, 2) void k_gemm3(
    const unsigned short* __restrict__ Aint,   // MPint, BB rows (split)
    const unsigned short* __restrict__ Bm,     // W2 split k-major
    const float* __restrict__ bias,
    float* __restrict__ outF)
{
    __shared__ __align__(16) unsigned short As2[2][128 * 64];
    const int tid  = threadIdx.x;
    const int lane = tid & 63, w = tid >> 6;
    const int wr = w >> 1, wc = w & 1;
    const int lr = lane & 15, cb = lane >> 4;
    const int sw = lr & 7;
    const long long row0 = (long long)blockIdx.x * 128;

    const size_t brow = (size_t)(wc * 144 + lr) * 64;
    const unsigned short* __restrict__ bhp = Bm + brow + ((cb ^ sw) << 3);
    const unsigned short* __restrict__ blp = Bm + brow + (((cb + 4) ^ sw) << 3);

    f32x4 acc[4][9];
    #pragma unroll
    for (int mf = 0; mf < 4; ++mf)
        #pragma unroll
        for (int nf = 0; nf < 9; ++nf)
            acc[mf][nf] = (f32x4){0.f, 0.f, 0.f, 0.f};

    auto stageA = [&](unsigned short* dst, int kt32) {
        const unsigned short* src = Aint + ((long long)kt32 * BB + row0) * 64;
        #pragma unroll
        for (int i = 0; i < 4; ++i) {
            const int cid = tid + i * 256;
            async16(src + (long long)cid * 8, dst + cid * 8);
        }
    };

    stageA(As2[0], 0);
    for (int t = 0; t < 9; ++t) {
        __syncthreads();
        if (t < 8) stageA(As2[(t + 1) & 1], t + 1);
        const unsigned short* As = As2[t & 1];
        short8 ah[4], al[4];
        #pragma unroll
        for (int mf = 0; mf < 4; ++mf) {
            const int m = wr * 64 + mf * 16 + lr;
            ah[mf] = *reinterpret_cast<const short8*>(&As[m * 64 + ((cb ^ sw) << 3)]);
            al[mf] = *reinterpret_cast<const short8*>(&As[m * 64 + (((cb + 4) ^ sw) << 3)]);
        }
        const long long toff = (long long)t * DP * 64;
        #pragma unroll
        for (int nf = 0; nf < 9; ++nf) {
            const long long d = toff + (long long)nf * 1024;
            const short8 bh = *reinterpret_cast<const short8*>(bhp + d);
            const short8 bl = *reinterpret_cast<const short8*>(blp + d);
            #pragma unroll
            for (int mf = 0; mf < 4; ++mf) {
                acc[mf][nf] = __builtin_amdgcn_mfma_f32_16x16x32_bf16(ah[mf], bh, acc[mf][nf], 0, 0, 0);
                acc[mf][nf] = __builtin_amdgcn_mfma_f32_16x16x32_bf16(al[mf], bh, acc[mf][nf], 0, 0, 0);
                acc[mf][nf] = __builtin_amdgcn_mfma_f32_16x16x32_bf16(ah[mf], bl, acc[mf][nf], 0, 0, 0);
            }
        }
    }

    #pragma unroll
    for (int mf = 0; mf < 4; ++mf) {
        const long long rb = row0 + wr * 64 + mf * 16 + ((lane >> 4) * 4);
        #pragma unroll
        for (int nf = 0; nf < 9; ++nf) {
            const int col = wc * 144 + nf * 16 + lr;
            const float bv = (col < DD) ? bias[col] : 0.0f;
            #pragma unroll
            for (int rr = 0; rr < 4; ++rr)
                outF[(rb + rr) * DP + col] = acc[mf][nf][rr] + bv;
        }
    }
}

// ---------------------------------------------------------------------------
__global__ __launch_bounds__(256) void k_stats(const float* __restrict__ seq, float* __restrict__ stats)
{
    __shared__ float s1[256], s2[256];
    const int d = blockIdx.x;
    float a = 0.f, q = 0.f;
    for (int b = threadIdx.x; b < BB; b += 256) {
        float v = seq[(size_t)b * DP + d];
        a += v; q = fmaf(v, v, q);
    }
    s1[threadIdx.x] = a; s2[threadIdx.x] = q;
    __syncthreads();
    for (int o = 128; o > 0; o >>= 1) {
        if (threadIdx.x < o) { s1[threadIdx.x] += s1[threadIdx.x + o]; s2[threadIdx.x] += s2[threadIdx.x + o]; }
        __syncthreads();
    }
    if (threadIdx.x == 0) {
        float m = s1[0] * (1.0f / BB);
        float v = s2[0] * (1.0f / BB) - m * m;
        stats[d]      = m;
        stats[DD + d] = 1.0f / sqrtf(v + 1e-5f);
    }
}

__global__ __launch_bounds__(256) void k_bn(const float* __restrict__ seq, const float* __restrict__ stats,
                                            const float* __restrict__ g, const float* __restrict__ bt,
                                            float* __restrict__ out)
{
    const long long idx = (long long)blockIdx.x * 256 + threadIdx.x;
    if (idx < (long long)BB * DD) {
        const int d = (int)(idx % DD);
        const long long b = idx / DD;
        out[idx] = (seq[b * DP + d] - stats[d]) * stats[DD + d] * g[d] + bt[d];
    }
}

// ---------------------------------------------------------------------------
extern "C" void kernel_launch(void* const* d_in, const int* in_sizes, int n_in,
                              void* d_out, int out_size, void* d_ws, size_t ws_size,
                              hipStream_t stream)
{
    const float* G   = (const float*)d_in[0];
    const float* X   = (const float*)d_in[1];
    const float* gk  = (const float*)d_in[2];
    const float* gW  = (const float*)d_in[3];
    const float* lsv = (const float*)d_in[4];
    const float* W1  = (const float*)d_in[5];
    const float* b1  = (const float*)d_in[6];
    const float* W2  = (const float*)d_in[7];
    const float* b2  = (const float*)d_in[8];
    const float* gam = (const float*)d_in[9];
    const float* bet = (const float*)d_in[10];

    char* p = (char*)d_ws;
    auto alloc = [&](size_t bytes) { void* r = (void*)p; p += (bytes + 255) & ~(size_t)255; return r; };
    unsigned short* Yint   = (unsigned short*)alloc((size_t)NPL * MROWS * 64 * 2); // 107.5 MB
    unsigned short* Bint   = (unsigned short*)alloc((size_t)3 * WBE * 2);      // 1 MB
    unsigned short* Bsng   = (unsigned short*)alloc((size_t)2 * WBS * 2);      // 0.33 MB
    unsigned short* MPint  = (unsigned short*)alloc((size_t)BB * 576 * 2);     // 4.7 MB
    float*          coff   = (float*)alloc((size_t)NN * DD * 4);
    float*          seqsum = (float*)alloc((size_t)BB * DP * 4);               // 4.7 MB
    float*          seqF   = (float*)alloc((size_t)BB * DP * 4);
    float*          stats  = (float*)alloc(2 * DD * 4);

    hipMemsetAsync(seqsum, 0, (size_t)BB * DP * 4, stream);

    k_splitB<<<(3 * DP * DP + 255) / 256, 256, 0, stream>>>(gW, W1, W2, lsv, Bint, Bsng, coff);
    // merged wavelet + Y = M@X
    k_wav<<<BB, 256, 0, stream>>>(G, gk, X, Yint);

    // fused: node-sum of relu((coff*relu((M@X)@gW)) @ W1 + b1) -> seqsum
    k_fused<<<(unsigned)(MROWS / 256), 512, 0, stream>>>(Yint, Bsng, Bsng + WBS,
                                                         coff, b1, seqsum);
    // mean -> split layout for gemm3
    k_mp<<<BB, 320, 0, stream>>>(seqsum, MPint);
    // GEMM3: seq = mean @ W2 + b2
    k_gemm3<<<BB / 128, 256, 0, stream>>>(MPint, Bint + 2 * WBE, b2, seqF);
    k_stats<<<DD, 256, 0, stream>>>(seqF, stats);
    k_bn<<<(unsigned)(((long long)BB * DD + 255) / 256), 256, 0, stream>>>(seqF, stats, gam, bet, (float*)d_out);
}

// Round 28
// 466.356 us; speedup vs baseline: 1.0014x; 1.0014x over previous
//
#include <hip/hip_runtime.h>
#include <math.h>

namespace {
constexpr int BB = 4096;   // batch
constexpr int NN = 41;     // nodes
constexpr int DD = 271;    // features
constexpr int DP = 288;    // padded feature dim (multiple of 32)
constexpr int PW = 44;     // padded row stride for 41-wide LDS matrices
constexpr long long MROWS = (long long)BB * NN;   // 167936
constexpr int WBE = DP * DP * 2;     // per-weight split Bint stride (ushorts)
constexpr int WBS = (DP / 32) * DP * 32;  // per-weight single Bsng stride (ushorts)
constexpr int SROW = 312;            // fused-kernel S row stride (ushorts)
constexpr int NPL = 5;               // Y planes of 64 k (K padded to 320)
}

typedef __attribute__((ext_vector_type(8)))  unsigned short ushort8;
typedef __attribute__((ext_vector_type(8)))  short          short8;
typedef __attribute__((ext_vector_type(4)))  float          f32x4;

__device__ __forceinline__ unsigned short f2bf(float f) {
    unsigned u = __float_as_uint(f);
    unsigned r = (u + 0x7FFFu + ((u >> 16) & 1u)) >> 16;
    return (unsigned short)r;
}
__device__ __forceinline__ float bf2f(unsigned short h) {
    return __uint_as_float(((unsigned)h) << 16);
}

// ---------------------------------------------------------------------------
// split k-major layout (W2, MPint): element (row, k) of a plane with
// `nrows` rows at ((k>>5)*nrows + row)*64 + chunk^(row&7); hi 0..3, lo 4..7.
// ---------------------------------------------------------------------------
__device__ __forceinline__ void store_split_km(unsigned short* __restrict__ dst,
                                               long long nrows, long long row,
                                               int col, float v)
{
    const unsigned short hh = f2bf(v);
    const unsigned short ll = f2bf(v - bf2f(hh));
    const long long base = ((long long)(col >> 5) * nrows + row) * 64;
    const int cn = (col & 31) >> 3, k7 = col & 7, sw = (int)(row & 7);
    dst[base + ((cn ^ sw) << 3) + k7]       = hh;
    dst[base + (((cn + 4) ^ sw) << 3) + k7] = ll;
}

// ---------------------------------------------------------------------------
// LDS matmul helper: C = scale * A@B - (sub ? sub : 0), 41x41, stride-44 rows.
// ---------------------------------------------------------------------------
__device__ __forceinline__ void lds_mm(const float (*__restrict__ A)[PW],
                                       const float (*__restrict__ B)[PW],
                                       float (*__restrict__ C)[PW],
                                       const float scale,
                                       const float (*__restrict__ sub)[PW],
                                       const int tid)
{
    for (int s = tid; s < NN * 11; s += 256) {
        const int i = s / 11, q = s % 11;
        float4 acc = make_float4(0.f, 0.f, 0.f, 0.f);
        #pragma unroll
        for (int k = 0; k < NN; ++k) {
            const float a = A[i][k];
            const float4 b4 = *reinterpret_cast<const float4*>(&B[k][q * 4]);
            acc.x = fmaf(a, b4.x, acc.x); acc.y = fmaf(a, b4.y, acc.y);
            acc.z = fmaf(a, b4.z, acc.z); acc.w = fmaf(a, b4.w, acc.w);
        }
        float4 r;
        if (sub) {
            const float4 s4 = *reinterpret_cast<const float4*>(&sub[i][q * 4]);
            r = make_float4(fmaf(scale, acc.x, -s4.x), fmaf(scale, acc.y, -s4.y),
                            fmaf(scale, acc.z, -s4.z), fmaf(scale, acc.w, -s4.w));
        } else {
            r = make_float4(scale * acc.x, scale * acc.y, scale * acc.z, scale * acc.w);
        }
        *reinterpret_cast<float4*>(&C[i][q * 4]) = r;
    }
}

// ---------------------------------------------------------------------------
// K1: wavelet basis -> fused M = l1n(thr(W)) @ diag(gk) @ l1n(thr(Wi)).
// lambda via 3 squarings (L^16) + 4 matvecs. MT[b][j][i] = M[b][i][j].
// (r26 winner, unchanged: high-occupancy split kernel)
// ---------------------------------------------------------------------------
__global__ __launch_bounds__(256) void k_wavelet(const float* __restrict__ G,
                                                 const float* __restrict__ gk,
                                                 float* __restrict__ MT)
{
    __shared__ float sG[NN][PW];
    __shared__ float sL[NN][PW];
    __shared__ float sT2[NN][PW];
    __shared__ float sT3[NN][PW];
    __shared__ float sM[NN][PW];
    __shared__ float sdeg[NN], sdinv[NN], srs[NN];
    __shared__ float slam16;

    const int b   = blockIdx.x;
    const int tid = threadIdx.x;
    const float* Gb = G + (size_t)b * NN * NN;

    for (int e = tid; e < NN * PW; e += 256) {
        const int i = e / PW, j = e % PW;
        sG[i][j] = (j < NN) ? Gb[i * NN + j] : 0.0f;
    }
    __syncthreads();

    if (tid < NN) {
        float4 s4 = make_float4(0.f, 0.f, 0.f, 0.f);
        #pragma unroll
        for (int q = 0; q < 11; ++q) {
            const float4 g4 = *reinterpret_cast<const float4*>(&sG[tid][q * 4]);
            s4.x += g4.x; s4.y += g4.y; s4.z += g4.z; s4.w += g4.w;
        }
        const float s = (s4.x + s4.y) + (s4.z + s4.w);
        sdeg[tid]  = s;
        sdinv[tid] = 1.0f / (sqrtf(s) + 1e-6f);
    }
    __syncthreads();

    for (int e = tid; e < NN * PW; e += 256) {
        const int i = e / PW, j = e % PW;
        if (j < NN) {
            const float a = 0.5f * (sG[i][j] + sG[j][i]);
            const float v = ((i == j) ? sdeg[i] : 0.0f) - a;
            sL[i][j] = sdinv[i] * sdinv[j] * v;
        } else {
            sL[i][j] = 0.0f;
        }
    }
    __syncthreads();

    lds_mm(sL, sL, sT2, 2.0f, nullptr, tid);   // T2 = 2 L^2
    __syncthreads();
    lds_mm(sL, sT2, sT3, 2.0f, sL, tid);       // T3 = 2 L T2 - L
    __syncthreads();

    lds_mm(sT2, sT2, sM, 0.25f, nullptr, tid); // L^4
    __syncthreads();
    lds_mm(sM, sM, sG, 1.0f, nullptr, tid);    // L^8  -> sG
    __syncthreads();
    lds_mm(sG, sG, sM, 1.0f, nullptr, tid);    // L^16 -> sM
    __syncthreads();

    if (tid < 64) {
        float lr[NN];
        #pragma unroll
        for (int j = 0; j < NN; ++j) lr[j] = (tid < NN) ? sM[tid][j] : 0.0f;
        unsigned h = (unsigned)(tid + 1) * 2654435761u;
        h ^= h >> 13; h *= 0x85ebca6bu; h ^= h >> 16;
        float v = (tid < NN) ? (0.25f + (float)(h & 1023) * (1.0f / 1024.0f)) : 0.0f;
        float n2 = v * v;
        #pragma unroll
        for (int off = 32; off > 0; off >>= 1) n2 += __shfl_xor(n2, off, 64);
        v *= rsqrtf(n2);
        float lam = 1.0f;
        #pragma unroll
        for (int it = 0; it < 4; ++it) {
            float acc = 0.f;
            #pragma unroll
            for (int j = 0; j < NN; ++j) acc = fmaf(lr[j], __shfl(v, j, 64), acc);
            float m2 = acc * acc;
            #pragma unroll
            for (int off = 32; off > 0; off >>= 1) m2 += __shfl_xor(m2, off, 64);
            lam = sqrtf(m2);
            v = acc * (1.0f / lam);
        }
        if (tid == 0) slam16 = lam;
    }
    __syncthreads();

    const float x = 0.15f * exp2f(log2f(slam16) * (1.0f / 16.0f));
    float iv[4];
    {
        const float xh = 0.5f * x, xh2 = xh * xh;
        #pragma unroll
        for (int n = 0; n < 4; ++n) {
            float c = 1.0f;
            for (int q = 2; q <= n; ++q) c /= (float)q;
            float p = 1.0f;
            for (int q = 0; q < n; ++q) p *= xh;
            float s = 0.f;
            for (int k = 0; k < 25; ++k) {
                s += c * p;
                p *= xh2;
                c /= (float)((k + 1) * (k + 1 + n));
            }
            iv[n] = s;
        }
    }
    const float ex = expf(x), emx = expf(-x);

    // Wn = l1norm(thresh(W)) -> sM
    {
        const float a1 = 2.f * ex * iv[1], a2 = 2.f * ex * iv[2], a3 = 2.f * ex * iv[3];
        for (int s = tid; s < NN * 11; s += 256) {
            const int i = s / 11, q = s % 11;
            const float4 l4  = *reinterpret_cast<const float4*>(&sL[i][q * 4]);
            const float4 t24 = *reinterpret_cast<const float4*>(&sT2[i][q * 4]);
            const float4 t34 = *reinterpret_cast<const float4*>(&sT3[i][q * 4]);
            float4 w;
            w.x = fmaf(a1, l4.x, fmaf(a2, t24.x, a3 * t34.x));
            w.y = fmaf(a1, l4.y, fmaf(a2, t24.y, a3 * t34.y));
            w.z = fmaf(a1, l4.z, fmaf(a2, t24.z, a3 * t34.z));
            w.w = fmaf(a1, l4.w, fmaf(a2, t24.w, a3 * t34.w));
            w.x = (w.x < 1e-4f) ? 0.f : w.x;  w.y = (w.y < 1e-4f) ? 0.f : w.y;
            w.z = (w.z < 1e-4f) ? 0.f : w.z;  w.w = (w.w < 1e-4f) ? 0.f : w.w;
            *reinterpret_cast<float4*>(&sM[i][q * 4]) = w;
        }
        __syncthreads();
        if (tid < NN) {
            float s = 0.f;
            #pragma unroll
            for (int q = 0; q < 11; ++q) {
                const float4 w4 = *reinterpret_cast<const float4*>(&sM[tid][q * 4]);
                s += fabsf(w4.x) + fabsf(w4.y) + fabsf(w4.z) + fabsf(w4.w);
            }
            srs[tid] = 1.0f / fmaxf(s, 1e-12f);
        }
        __syncthreads();
    }
    // scale Wn rows; Win = thresh(Wi) -> sG
    {
        const float a1 = -2.f * emx * iv[1], a2 = 2.f * emx * iv[2], a3 = -2.f * emx * iv[3];
        for (int s = tid; s < NN * 11; s += 256) {
            const int i = s / 11, q = s % 11;
            float4 m4 = *reinterpret_cast<float4*>(&sM[i][q * 4]);
            const float rs = srs[i];
            m4.x *= rs; m4.y *= rs; m4.z *= rs; m4.w *= rs;
            *reinterpret_cast<float4*>(&sM[i][q * 4]) = m4;
            const float4 l4  = *reinterpret_cast<const float4*>(&sL[i][q * 4]);
            const float4 t24 = *reinterpret_cast<const float4*>(&sT2[i][q * 4]);
            const float4 t34 = *reinterpret_cast<const float4*>(&sT3[i][q * 4]);
            float4 w;
            w.x = fmaf(a1, l4.x, fmaf(a2, t24.x, a3 * t34.x));
            w.y = fmaf(a1, l4.y, fmaf(a2, t24.y, a3 * t34.y));
            w.z = fmaf(a1, l4.z, fmaf(a2, t24.z, a3 * t34.z));
            w.w = fmaf(a1, l4.w, fmaf(a2, t24.w, a3 * t34.w));
            w.x = (w.x < 1e-4f) ? 0.f : w.x;  w.y = (w.y < 1e-4f) ? 0.f : w.y;
            w.z = (w.z < 1e-4f) ? 0.f : w.z;  w.w = (w.w < 1e-4f) ? 0.f : w.w;
            *reinterpret_cast<float4*>(&sG[i][q * 4]) = w;
        }
        __syncthreads();
        if (tid < NN) {
            float s = 0.f;
            #pragma unroll
            for (int q = 0; q < 11; ++q) {
                const float4 w4 = *reinterpret_cast<const float4*>(&sG[tid][q * 4]);
                s += fabsf(w4.x) + fabsf(w4.y) + fabsf(w4.z) + fabsf(w4.w);
            }
            sdeg[tid] = gk[tid] / fmaxf(s, 1e-12f);
        }
        __syncthreads();
        for (int s = tid; s < NN * 11; s += 256) {
            const int j = s / 11, q = s % 11;
            float4 w4 = *reinterpret_cast<float4*>(&sG[j][q * 4]);
            const float rs = sdeg[j];
            w4.x *= rs; w4.y *= rs; w4.z *= rs; w4.w *= rs;
            *reinterpret_cast<float4*>(&sG[j][q * 4]) = w4;
        }
        __syncthreads();
    }
    lds_mm(sM, sG, sL, 1.0f, nullptr, tid);   // M = Wn @ diag(gk) Win
    __syncthreads();
    float* dst = MT + (size_t)b * NN * NN;
    for (int e = tid; e < NN * NN; e += 256) {
        const int j = e / NN, i = e % NN;
        dst[e] = sL[i][j];
    }
}

// ---------------------------------------------------------------------------
// Prep: weights -> split k-major Bint (W2 for gemm3) AND single-bf16
// k-major Bsng (gW, W1 for the fused kernel). Also coff = exp(lsv).
// ---------------------------------------------------------------------------
__global__ __launch_bounds__(256) void k_splitB(const float* __restrict__ gW,
                                                const float* __restrict__ W1,
                                                const float* __restrict__ W2,
                                                const float* __restrict__ lsv,
                                                unsigned short* __restrict__ Bint,
                                                unsigned short* __restrict__ Bsng,
                                                float* __restrict__ coff)
{
    const int t = blockIdx.x * 256 + threadIdx.x;
    if (t < NN * DD) coff[t] = expf(lsv[t]);
    if (t >= 3 * DP * DP) return;
    const int w = t / (DP * DP);
    const int r = t % (DP * DP);
    const int n = r / DP, k = r % DP;
    const float* src = (w == 0) ? gW : ((w == 1) ? W1 : W2);
    const float v = (n < DD && k < DD) ? src[k * DD + n] : 0.0f;
    store_split_km(Bint + (size_t)w * WBE, DP, n, k, v);
    if (w < 2) {
        Bsng[(size_t)w * WBS + ((long long)(k >> 5) * DP + n) * 32 +
             (((k & 31) >> 3) << 3) + (k & 7)] = f2bf(v);
    }
}

// ---------------------------------------------------------------------------
// K2 v10 (MFMA, half-staged): Y = M @ X per sample -> single-bf16 planes.
// sXT holds ONE 144-col half of X^T at a time (19.6 KB instead of 39 KB),
// two stage+MFMA passes; X still read exactly once. LDS 50.4 KB ->
// 3 blocks/CU (was 2) for this memory-bound kernel.
// ---------------------------------------------------------------------------
__global__ __launch_bounds__(256, 3) void k_wavX(const float* __restrict__ MT,
                                                 const float* __restrict__ X,
                                                 unsigned short* __restrict__ Yint)
{
    constexpr int XJ  = 68;                    // j-stride (136B rows)
    constexpr int YST = 296;                   // sYb col stride
    constexpr int HC  = 144;                   // columns per half
    __shared__ __align__(16) unsigned short sXT[HC * XJ];   // 19584 B
    __shared__ __align__(16) unsigned short sMm[48 * XJ];   //  6528 B
    __shared__ __align__(16) unsigned short sYb[NN * YST];  // 24272 B
    const int b   = blockIdx.x;
    const int tid = threadIdx.x;
    const int lane = tid & 63, w = tid >> 6;
    const int lr = lane & 15;
    const int hi8 = (lane >> 4) * 8;

    const ushort8 z8 = {0, 0, 0, 0, 0, 0, 0, 0};
    for (int e = tid; e < (48 * XJ) / 8; e += 256)
        *reinterpret_cast<ushort8*>(&sMm[e * 8]) = z8;
    __syncthreads();

    // stage M: sMm[i][j] = bf16(M[i][j]) = bf16(MT[b][j*41+i]); coalesced
    const float* __restrict__ Mb = MT + (size_t)b * NN * NN;
    for (int e = tid; e < NN * NN; e += 256) {
        const int j = e / NN, i = e % NN;
        sMm[i * XJ + j] = f2bf(Mb[e]);
    }

    const float* __restrict__ Xb = X + (size_t)b * NN * DD;
    #pragma unroll
    for (int h = 0; h < 2; ++h) {
        __syncthreads();       // h=0: M staged; h=1: prev-half MFMA reads done
        for (int e = tid; e < (HC * XJ) / 8; e += 256)
            *reinterpret_cast<ushort8*>(&sXT[e * 8]) = z8;
        __syncthreads();
        // stage X^T half: sXT[lc][j] = bf16(X[b][j][h*144+lc])
        for (int e = tid; e < NN * HC; e += 256) {
            const int j = e / HC, lc = e % HC;
            const int c = h * HC + lc;
            if (c < DD) sXT[lc * XJ + j] = f2bf(Xb[j * DD + c]);
        }
        __syncthreads();

        // MFMA: 3 m-tiles x 9 n-tiles of 16x16, K = 64 (2 steps of 32)
        for (int t = w; t < 27; t += 4) {
            const int mt = t / 9, nt = t % 9;
            f32x4 acc = (f32x4){0.f, 0.f, 0.f, 0.f};
            #pragma unroll
            for (int ks = 0; ks < 2; ++ks) {
                const short8 a = *reinterpret_cast<const short8*>(
                    &sMm[(mt * 16 + lr) * XJ + ks * 32 + hi8]);
                const short8 bf = *reinterpret_cast<const short8*>(
                    &sXT[(nt * 16 + lr) * XJ + ks * 32 + hi8]);
                acc = __builtin_amdgcn_mfma_f32_16x16x32_bf16(a, bf, acc, 0, 0, 0);
            }
            const int row0 = mt * 16 + (lane >> 4) * 4;
            const int col  = h * HC + nt * 16 + lr;
            #pragma unroll
            for (int rr = 0; rr < 4; ++rr) {
                const int row = row0 + rr;
                if (row < NN) sYb[row * YST + col] = f2bf(acc[rr]);
            }
        }
    }
    __syncthreads();

    // repack to Yint plane layout with 16B stores
    for (int t = tid; t < NN * 36; t += 256) {
        const int i = t / 36, c8 = t % 36;
        const ushort8 hv = *reinterpret_cast<const ushort8*>(&sYb[i * YST + c8 * 8]);
        const long long r = (long long)b * NN + i;
        const int p = c8 >> 3;                           // plane (64k)
        const int chunk = ((c8 >> 2) & 1) * 4 + (c8 & 3);
        const int sw = (int)(r & 7);
        unsigned short* base = Yint + ((long long)p * MROWS + r) * 64;
        *reinterpret_cast<ushort8*>(base + ((chunk ^ sw) << 3)) = hv;
    }
}

// ---------------------------------------------------------------------------
__device__ __forceinline__ void async16(const unsigned short* __restrict__ g,
                                        unsigned short* l)
{
    __builtin_amdgcn_global_load_lds(
        (const __attribute__((address_space(1))) unsigned int*)g,
        (__attribute__((address_space(3))) unsigned int*)l, 16, 0, 0);
}

// ---------------------------------------------------------------------------
// K3 v11: FUSED GEMM1+GEMM2+NODE-MEAN, atomic-free hot path (r26 winner).
// ---------------------------------------------------------------------------
__global__ __launch_bounds__(512, 2) void k_fused(
    const unsigned short* __restrict__ Aint,   // Y, single k-major planes
    const unsigned short* __restrict__ Bs0,    // gW single k-major
    const unsigned short* __restrict__ Bs1,    // W1 single k-major
    const float* __restrict__ coff,
    const float* __restrict__ b1,
    float* __restrict__ seqsum)                // [BB][DP] f32, pre-zeroed
{
    __shared__ __align__(16) unsigned short sS[256 * SROW];     // 156 KB
    const int tid  = threadIdx.x;
    const int lane = tid & 63, w = tid >> 6;    // 8 waves
    const int wr = w >> 1, wc = w & 1;          // wr 0..3 (64-row groups)
    const int lr = lane & 15, cb = lane >> 4;
    const int sw = lr & 7;

    const int nwg = gridDim.x, orig = blockIdx.x;
    const int q = nwg >> 3, r = nwg & 7;
    const int xcd = orig & 7, loc = orig >> 3;
    const int bid = (xcd < r ? xcd * (q + 1) : r * (q + 1) + (xcd - r) * q) + loc;
    const long long row0 = (long long)bid * 256;

    const unsigned short* __restrict__ b0p = Bs0 + (size_t)(wc * 144 + lr) * 32 + cb * 8;
    const unsigned short* __restrict__ b1p = Bs1 + (size_t)(wc * 144 + lr) * 32 + cb * 8;

    f32x4 acc[4][9];
    #pragma unroll
    for (int mf = 0; mf < 4; ++mf)
        #pragma unroll
        for (int nf = 0; nf < 9; ++nf)
            acc[mf][nf] = (f32x4){0.f, 0.f, 0.f, 0.f};

    // ---------------- phase 1: acc = Y @ gW  (NO barriers) ----------------
    for (int t = 0; t < 9; ++t) {
        const int p  = t >> 1;
        const int hc = (t & 1) * 4 + cb;
        const long long abase = ((long long)p * MROWS + row0) * 64 + ((hc ^ sw) << 3);
        short8 a[4];
        #pragma unroll
        for (int mf = 0; mf < 4; ++mf)
            a[mf] = *reinterpret_cast<const short8*>(
                Aint + abase + (long long)(wr * 64 + mf * 16 + lr) * 64);
        const long long toff = (long long)t * DP * 32;
        #pragma unroll
        for (int nf = 0; nf < 9; ++nf) {
            const short8 bh = *reinterpret_cast<const short8*>(b0p + toff + (long long)nf * 512);
            #pragma unroll
            for (int mf = 0; mf < 4; ++mf)
                acc[mf][nf] = __builtin_amdgcn_mfma_f32_16x16x32_bf16(a[mf], bh, acc[mf][nf], 0, 0, 0);
        }
    }

    // epilogue 1: S = coff*relu(acc) -> sS (pad cols get coff 0 -> S=0)
    #pragma unroll
    for (int mf = 0; mf < 4; ++mf) {
        const int mb = wr * 64 + mf * 16 + ((lane >> 4) * 4);
        #pragma unroll
        for (int nf = 0; nf < 9; ++nf) {
            const int col = wc * 144 + nf * 16 + lr;
            #pragma unroll
            for (int rr = 0; rr < 4; ++rr) {
                const int m = mb + rr;
                float v = fmaxf(acc[mf][nf][rr], 0.f);
                const float cf = (col < DD) ? coff[((unsigned)(row0 + m) % 41u) * DD + col] : 0.0f;
                sS[m * SROW + col] = f2bf(v * cf);
                acc[mf][nf][rr] = 0.f;
            }
        }
    }
    __syncthreads();   // S complete before cross-wave reads

    // ---------------- phase 2: acc = S @ W1 (single A from LDS, single B) --
    for (int t = 0; t < 9; ++t) {
        short8 ah[4];
        #pragma unroll
        for (int mf = 0; mf < 4; ++mf) {
            const int m = wr * 64 + mf * 16 + lr;
            ah[mf] = *reinterpret_cast<const short8*>(&sS[m * SROW + t * 32 + cb * 8]);
        }
        const long long toff = (long long)t * DP * 32;
        #pragma unroll
        for (int nf = 0; nf < 9; ++nf) {
            const short8 bh = *reinterpret_cast<const short8*>(b1p + toff + (long long)nf * 512);
            #pragma unroll
            for (int mf = 0; mf < 4; ++mf)
                acc[mf][nf] = __builtin_amdgcn_mfma_f32_16x16x32_bf16(ah[mf], bh, acc[mf][nf], 0, 0, 0);
        }
    }
    __syncthreads();   // all phase-2 sS reads complete before overwrite

    // epilogue 2a: P2 values (bf16) -> sS, own rows only (no hazards)
    #pragma unroll
    for (int mf = 0; mf < 4; ++mf) {
        const int mb = wr * 64 + mf * 16 + ((lane >> 4) * 4);
        #pragma unroll
        for (int nf = 0; nf < 9; ++nf) {
            const int col = wc * 144 + nf * 16 + lr;
            const float bv = (col < DD) ? b1[col] : 0.0f;
            #pragma unroll
            for (int rr = 0; rr < 4; ++rr) {
                const float v = fmaxf(acc[mf][nf][rr] + bv, 0.f);
                sS[(mb + rr) * SROW + col] = f2bf(v);
            }
        }
    }
    __syncthreads();

    // epilogue 2b: cooperative node-sum, then one global atomicAdd each
    const long long b0 = row0 / 41;
    for (int e = tid; e < 8 * DP; e += 512) {
        const int ls = e / DP, col = e % DP;
        const long long bsm = b0 + ls;
        if (bsm >= BB) continue;
        const long long gr0 = bsm * 41, gr1 = gr0 + 41;
        const int m0 = (int)((gr0 > row0 ? gr0 : row0) - row0);
        const long long hi = (gr1 < row0 + 256 ? gr1 : row0 + 256);
        const int m1 = (int)(hi - row0);
        if (m0 >= m1) continue;
        float s = 0.f;
        for (int m = m0; m < m1; ++m) s += bf2f(sS[m * SROW + col]);
        atomicAdd(&seqsum[bsm * DP + col], s);
    }
}

// ---------------------------------------------------------------------------
// K5: seqsum/41 -> split k-major MPint (BB rows).
// ---------------------------------------------------------------------------
__global__ __launch_bounds__(320) void k_mp(const float* __restrict__ seqsum,
                                            unsigned short* __restrict__ MPint)
{
    const int b = blockIdx.x;
    const int c = threadIdx.x;
    if (c >= DP) return;
    store_split_km(MPint, BB, b, c, seqsum[(size_t)b * DP + c] * (1.0f / 41.0f));
}

// ---------------------------------------------------------------------------
// K6: GEMM3 (small): seq = mean @ W2 + b2 (split path, unchanged).
// ---------------------------------------------------------------------------
__global__ __launch_bounds__(256, 2) void k_gemm3(
    const unsigned short* __restrict__ Aint,   // MPint, BB rows (split)
    const unsigned short* __restrict__ Bm,     // W2 split k-major
    const float* __restrict__ bias,
    float* __restrict__ outF)
{
    __shared__ __align__(16) unsigned short As2[2][128 * 64];
    const int tid  = threadIdx.x;
    const int lane = tid & 63, w = tid >> 6;
    const int wr = w >> 1, wc = w & 1;
    const int lr = lane & 15, cb = lane >> 4;
    const int sw = lr & 7;
    const long long row0 = (long long)blockIdx.x * 128;

    const size_t brow = (size_t)(wc * 144 + lr) * 64;
    const unsigned short* __restrict__ bhp = Bm + brow + ((cb ^ sw) << 3);
    const unsigned short* __restrict__ blp = Bm + brow + (((cb + 4) ^ sw) << 3);

    f32x4 acc[4][9];
    #pragma unroll
    for (int mf = 0; mf < 4; ++mf)
        #pragma unroll
        for (int nf = 0; nf < 9; ++nf)
            acc[mf][nf] = (f32x4){0.f, 0.f, 0.f, 0.f};

    auto stageA = [&](unsigned short* dst, int kt32) {
        const unsigned short* src = Aint + ((long long)kt32 * BB + row0) * 64;
        #pragma unroll
        for (int i = 0; i < 4; ++i) {
            const int cid = tid + i * 256;
            async16(src + (long long)cid * 8, dst + cid * 8);
        }
    };

    stageA(As2[0], 0);
    for (int t = 0; t < 9; ++t) {
        __syncthreads();
        if (t < 8) stageA(As2[(t + 1) & 1], t + 1);
        const unsigned short* As = As2[t & 1];
        short8 ah[4], al[4];
        #pragma unroll
        for (int mf = 0; mf < 4; ++mf) {
            const int m = wr * 64 + mf * 16 + lr;
            ah[mf] = *reinterpret_cast<const short8*>(&As[m * 64 + ((cb ^ sw) << 3)]);
            al[mf] = *reinterpret_cast<const short8*>(&As[m * 64 + (((cb + 4) ^ sw) << 3)]);
        }
        const long long toff = (long long)t * DP * 64;
        #pragma unroll
        for (int nf = 0; nf < 9; ++nf) {
            const long long d = toff + (long long)nf * 1024;
            const short8 bh = *reinterpret_cast<const short8*>(bhp + d);
            const short8 bl = *reinterpret_cast<const short8*>(blp + d);
            #pragma unroll
            for (int mf = 0; mf < 4; ++mf) {
                acc[mf][nf] = __builtin_amdgcn_mfma_f32_16x16x32_bf16(ah[mf], bh, acc[mf][nf], 0, 0, 0);
                acc[mf][nf] = __builtin_amdgcn_mfma_f32_16x16x32_bf16(al[mf], bh, acc[mf][nf], 0, 0, 0);
                acc[mf][nf] = __builtin_amdgcn_mfma_f32_16x16x32_bf16(ah[mf], bl, acc[mf][nf], 0, 0, 0);
            }
        }
    }

    #pragma unroll
    for (int mf = 0; mf < 4; ++mf) {
        const long long rb = row0 + wr * 64 + mf * 16 + ((lane >> 4) * 4);
        #pragma unroll
        for (int nf = 0; nf < 9; ++nf) {
            const int col = wc * 144 + nf * 16 + lr;
            const float bv = (col < DD) ? bias[col] : 0.0f;
            #pragma unroll
            for (int rr = 0; rr < 4; ++rr)
                outF[(rb + rr) * DP + col] = acc[mf][nf][rr] + bv;
        }
    }
}

// ---------------------------------------------------------------------------
__global__ __launch_bounds__(256) void k_stats(const float* __restrict__ seq, float* __restrict__ stats)
{
    __shared__ float s1[256], s2[256];
    const int d = blockIdx.x;
    float a = 0.f, q = 0.f;
    for (int b = threadIdx.x; b < BB; b += 256) {
        float v = seq[(size_t)b * DP + d];
        a += v; q = fmaf(v, v, q);
    }
    s1[threadIdx.x] = a; s2[threadIdx.x] = q;
    __syncthreads();
    for (int o = 128; o > 0; o >>= 1) {
        if (threadIdx.x < o) { s1[threadIdx.x] += s1[threadIdx.x + o]; s2[threadIdx.x] += s2[threadIdx.x + o]; }
        __syncthreads();
    }
    if (threadIdx.x == 0) {
        float m = s1[0] * (1.0f / BB);
        float v = s2[0] * (1.0f / BB) - m * m;
        stats[d]      = m;
        stats[DD + d] = 1.0f / sqrtf(v + 1e-5f);
    }
}

__global__ __launch_bounds__(256) void k_bn(const float* __restrict__ seq, const float* __restrict__ stats,
                                            const float* __restrict__ g, const float* __restrict__ bt,
                                            float* __restrict__ out)
{
    const long long idx = (long long)blockIdx.x * 256 + threadIdx.x;
    if (idx < (long long)BB * DD) {
        const int d = (int)(idx % DD);
        const long long b = idx / DD;
        out[idx] = (seq[b * DP + d] - stats[d]) * stats[DD + d] * g[d] + bt[d];
    }
}

// ---------------------------------------------------------------------------
extern "C" void kernel_launch(void* const* d_in, const int* in_sizes, int n_in,
                              void* d_out, int out_size, void* d_ws, size_t ws_size,
                              hipStream_t stream)
{
    const float* G   = (const float*)d_in[0];
    const float* X   = (const float*)d_in[1];
    const float* gk  = (const float*)d_in[2];
    const float* gW  = (const float*)d_in[3];
    const float* lsv = (const float*)d_in[4];
    const float* W1  = (const float*)d_in[5];
    const float* b1  = (const float*)d_in[6];
    const float* W2  = (const float*)d_in[7];
    const float* b2  = (const float*)d_in[8];
    const float* gam = (const float*)d_in[9];
    const float* bet = (const float*)d_in[10];

    char* p = (char*)d_ws;
    auto alloc = [&](size_t bytes) { void* r = (void*)p; p += (bytes + 255) & ~(size_t)255; return r; };
    float*          MT     = (float*)alloc((size_t)BB * NN * NN * 4);          // 27.5 MB
    unsigned short* Yint   = (unsigned short*)alloc((size_t)NPL * MROWS * 64 * 2); // 107.5 MB
    unsigned short* Bint   = (unsigned short*)alloc((size_t)3 * WBE * 2);      // 1 MB
    unsigned short* Bsng   = (unsigned short*)alloc((size_t)2 * WBS * 2);      // 0.33 MB
    unsigned short* MPint  = (unsigned short*)alloc((size_t)BB * 576 * 2);     // 4.7 MB
    float*          coff   = (float*)alloc((size_t)NN * DD * 4);
    float*          seqsum = (float*)alloc((size_t)BB * DP * 4);               // 4.7 MB
    float*          seqF   = (float*)alloc((size_t)BB * DP * 4);
    float*          stats  = (float*)alloc(2 * DD * 4);

    hipMemsetAsync(seqsum, 0, (size_t)BB * DP * 4, stream);

    k_wavelet<<<BB, 256, 0, stream>>>(G, gk, MT);
    k_splitB<<<(3 * DP * DP + 255) / 256, 256, 0, stream>>>(gW, W1, W2, lsv, Bint, Bsng, coff);
    k_wavX<<<BB, 256, 0, stream>>>(MT, X, Yint);

    // fused: node-sum of relu((coff*relu((M@X)@gW)) @ W1 + b1) -> seqsum
    k_fused<<<(unsigned)(MROWS / 256), 512, 0, stream>>>(Yint, Bsng, Bsng + WBS,
                                                         coff, b1, seqsum);
    // mean -> split layout for gemm3
    k_mp<<<BB, 320, 0, stream>>>(seqsum, MPint);
    // GEMM3: seq = mean @ W2 + b2
    k_gemm3<<<BB / 128, 256, 0, stream>>>(MPint, Bint + 2 * WBE, b2, seqF);
    k_stats<<<DD, 256, 0, stream>>>(seqF, stats);
    k_bn<<<(unsigned)(((long long)BB * DD + 255) / 256), 256, 0, stream>>>(seqF, stats, gam, bet, (float*)d_out);
}

// Round 29
// 416.136 us; speedup vs baseline: 1.1223x; 1.1207x over previous
//
#include <hip/hip_runtime.h>
#include <math.h>

namespace {
constexpr int BB = 4096;   // batch
constexpr int NN = 41;     // nodes
constexpr int DD = 271;    // features
constexpr int DP = 288;    // padded feature dim (multiple of 32)
constexpr int PW = 44;     // padded row stride for 41-wide LDS matrices
constexpr long long MROWS = (long long)BB * NN;   // 167936
constexpr int WBE = DP * DP * 2;     // per-weight split Bint stride (ushorts)
constexpr int WBS = (DP / 32) * DP * 32;  // per-weight single Bsng stride (ushorts)
constexpr int SROW = 312;            // fused-kernel S row stride (ushorts)
constexpr int NPL = 5;               // Y planes of 64 k (K padded to 320)
constexpr int WT = 512;              // k_wavelet thread count (1-round lds_mm)
}

typedef __attribute__((ext_vector_type(8)))  unsigned short ushort8;
typedef __attribute__((ext_vector_type(8)))  short          short8;
typedef __attribute__((ext_vector_type(4)))  float          f32x4;

__device__ __forceinline__ unsigned short f2bf(float f) {
    unsigned u = __float_as_uint(f);
    unsigned r = (u + 0x7FFFu + ((u >> 16) & 1u)) >> 16;
    return (unsigned short)r;
}
__device__ __forceinline__ float bf2f(unsigned short h) {
    return __uint_as_float(((unsigned)h) << 16);
}

// ---------------------------------------------------------------------------
// split k-major layout (W2, MPint): element (row, k) of a plane with
// `nrows` rows at ((k>>5)*nrows + row)*64 + chunk^(row&7); hi 0..3, lo 4..7.
// ---------------------------------------------------------------------------
__device__ __forceinline__ void store_split_km(unsigned short* __restrict__ dst,
                                               long long nrows, long long row,
                                               int col, float v)
{
    const unsigned short hh = f2bf(v);
    const unsigned short ll = f2bf(v - bf2f(hh));
    const long long base = ((long long)(col >> 5) * nrows + row) * 64;
    const int cn = (col & 31) >> 3, k7 = col & 7, sw = (int)(row & 7);
    dst[base + ((cn ^ sw) << 3) + k7]       = hh;
    dst[base + (((cn + 4) ^ sw) << 3) + k7] = ll;
}

// ---------------------------------------------------------------------------
// LDS matmul helper: C = scale * A@B - (sub ? sub : 0), 41x41, stride-44 rows.
// WT=512 threads: 451 tasks -> ONE strided round (halved critical path).
// ---------------------------------------------------------------------------
__device__ __forceinline__ void lds_mm(const float (*__restrict__ A)[PW],
                                       const float (*__restrict__ B)[PW],
                                       float (*__restrict__ C)[PW],
                                       const float scale,
                                       const float (*__restrict__ sub)[PW],
                                       const int tid)
{
    for (int s = tid; s < NN * 11; s += WT) {
        const int i = s / 11, q = s % 11;
        float4 acc = make_float4(0.f, 0.f, 0.f, 0.f);
        #pragma unroll
        for (int k = 0; k < NN; ++k) {
            const float a = A[i][k];
            const float4 b4 = *reinterpret_cast<const float4*>(&B[k][q * 4]);
            acc.x = fmaf(a, b4.x, acc.x); acc.y = fmaf(a, b4.y, acc.y);
            acc.z = fmaf(a, b4.z, acc.z); acc.w = fmaf(a, b4.w, acc.w);
        }
        float4 r;
        if (sub) {
            const float4 s4 = *reinterpret_cast<const float4*>(&sub[i][q * 4]);
            r = make_float4(fmaf(scale, acc.x, -s4.x), fmaf(scale, acc.y, -s4.y),
                            fmaf(scale, acc.z, -s4.z), fmaf(scale, acc.w, -s4.w));
        } else {
            r = make_float4(scale * acc.x, scale * acc.y, scale * acc.z, scale * acc.w);
        }
        *reinterpret_cast<float4*>(&C[i][q * 4]) = r;
    }
}

// ---------------------------------------------------------------------------
// K1: wavelet basis -> fused M = l1n(thr(W)) @ diag(gk) @ l1n(thr(Wi)).
// lambda via 3 squarings (L^16) + 4 matvecs. MT[b][j][i] = M[b][i][j].
// 512 threads: every lds_mm is one round; 4 blocks/CU -> 32 waves/CU.
// ---------------------------------------------------------------------------
__global__ __launch_bounds__(WT) void k_wavelet(const float* __restrict__ G,
                                                const float* __restrict__ gk,
                                                float* __restrict__ MT)
{
    __shared__ float sG[NN][PW];
    __shared__ float sL[NN][PW];
    __shared__ float sT2[NN][PW];
    __shared__ float sT3[NN][PW];
    __shared__ float sM[NN][PW];
    __shared__ float sdeg[NN], sdinv[NN], srs[NN];
    __shared__ float slam16;

    const int b   = blockIdx.x;
    const int tid = threadIdx.x;
    const float* Gb = G + (size_t)b * NN * NN;

    for (int e = tid; e < NN * PW; e += WT) {
        const int i = e / PW, j = e % PW;
        sG[i][j] = (j < NN) ? Gb[i * NN + j] : 0.0f;
    }
    __syncthreads();

    if (tid < NN) {
        float4 s4 = make_float4(0.f, 0.f, 0.f, 0.f);
        #pragma unroll
        for (int q = 0; q < 11; ++q) {
            const float4 g4 = *reinterpret_cast<const float4*>(&sG[tid][q * 4]);
            s4.x += g4.x; s4.y += g4.y; s4.z += g4.z; s4.w += g4.w;
        }
        const float s = (s4.x + s4.y) + (s4.z + s4.w);
        sdeg[tid]  = s;
        sdinv[tid] = 1.0f / (sqrtf(s) + 1e-6f);
    }
    __syncthreads();

    for (int e = tid; e < NN * PW; e += WT) {
        const int i = e / PW, j = e % PW;
        if (j < NN) {
            const float a = 0.5f * (sG[i][j] + sG[j][i]);
            const float v = ((i == j) ? sdeg[i] : 0.0f) - a;
            sL[i][j] = sdinv[i] * sdinv[j] * v;
        } else {
            sL[i][j] = 0.0f;
        }
    }
    __syncthreads();

    lds_mm(sL, sL, sT2, 2.0f, nullptr, tid);   // T2 = 2 L^2
    __syncthreads();
    lds_mm(sL, sT2, sT3, 2.0f, sL, tid);       // T3 = 2 L T2 - L
    __syncthreads();

    lds_mm(sT2, sT2, sM, 0.25f, nullptr, tid); // L^4
    __syncthreads();
    lds_mm(sM, sM, sG, 1.0f, nullptr, tid);    // L^8  -> sG
    __syncthreads();
    lds_mm(sG, sG, sM, 1.0f, nullptr, tid);    // L^16 -> sM
    __syncthreads();

    if (tid < 64) {
        float lr[NN];
        #pragma unroll
        for (int j = 0; j < NN; ++j) lr[j] = (tid < NN) ? sM[tid][j] : 0.0f;
        unsigned h = (unsigned)(tid + 1) * 2654435761u;
        h ^= h >> 13; h *= 0x85ebca6bu; h ^= h >> 16;
        float v = (tid < NN) ? (0.25f + (float)(h & 1023) * (1.0f / 1024.0f)) : 0.0f;
        float n2 = v * v;
        #pragma unroll
        for (int off = 32; off > 0; off >>= 1) n2 += __shfl_xor(n2, off, 64);
        v *= rsqrtf(n2);
        float lam = 1.0f;
        #pragma unroll
        for (int it = 0; it < 4; ++it) {
            float acc = 0.f;
            #pragma unroll
            for (int j = 0; j < NN; ++j) acc = fmaf(lr[j], __shfl(v, j, 64), acc);
            float m2 = acc * acc;
            #pragma unroll
            for (int off = 32; off > 0; off >>= 1) m2 += __shfl_xor(m2, off, 64);
            lam = sqrtf(m2);
            v = acc * (1.0f / lam);
        }
        if (tid == 0) slam16 = lam;
    }
    __syncthreads();

    const float x = 0.15f * exp2f(log2f(slam16) * (1.0f / 16.0f));
    float iv[4];
    {
        const float xh = 0.5f * x, xh2 = xh * xh;
        #pragma unroll
        for (int n = 0; n < 4; ++n) {
            float c = 1.0f;
            for (int q = 2; q <= n; ++q) c /= (float)q;
            float p = 1.0f;
            for (int q = 0; q < n; ++q) p *= xh;
            float s = 0.f;
            for (int k = 0; k < 25; ++k) {
                s += c * p;
                p *= xh2;
                c /= (float)((k + 1) * (k + 1 + n));
            }
            iv[n] = s;
        }
    }
    const float ex = expf(x), emx = expf(-x);

    // Wn = l1norm(thresh(W)) -> sM
    {
        const float a1 = 2.f * ex * iv[1], a2 = 2.f * ex * iv[2], a3 = 2.f * ex * iv[3];
        for (int s = tid; s < NN * 11; s += WT) {
            const int i = s / 11, q = s % 11;
            const float4 l4  = *reinterpret_cast<const float4*>(&sL[i][q * 4]);
            const float4 t24 = *reinterpret_cast<const float4*>(&sT2[i][q * 4]);
            const float4 t34 = *reinterpret_cast<const float4*>(&sT3[i][q * 4]);
            float4 w;
            w.x = fmaf(a1, l4.x, fmaf(a2, t24.x, a3 * t34.x));
            w.y = fmaf(a1, l4.y, fmaf(a2, t24.y, a3 * t34.y));
            w.z = fmaf(a1, l4.z, fmaf(a2, t24.z, a3 * t34.z));
            w.w = fmaf(a1, l4.w, fmaf(a2, t24.w, a3 * t34.w));
            w.x = (w.x < 1e-4f) ? 0.f : w.x;  w.y = (w.y < 1e-4f) ? 0.f : w.y;
            w.z = (w.z < 1e-4f) ? 0.f : w.z;  w.w = (w.w < 1e-4f) ? 0.f : w.w;
            *reinterpret_cast<float4*>(&sM[i][q * 4]) = w;
        }
        __syncthreads();
        if (tid < NN) {
            float s = 0.f;
            #pragma unroll
            for (int q = 0; q < 11; ++q) {
                const float4 w4 = *reinterpret_cast<const float4*>(&sM[tid][q * 4]);
                s += fabsf(w4.x) + fabsf(w4.y) + fabsf(w4.z) + fabsf(w4.w);
            }
            srs[tid] = 1.0f / fmaxf(s, 1e-12f);
        }
        __syncthreads();
    }
    // scale Wn rows; Win = thresh(Wi) -> sG
    {
        const float a1 = -2.f * emx * iv[1], a2 = 2.f * emx * iv[2], a3 = -2.f * emx * iv[3];
        for (int s = tid; s < NN * 11; s += WT) {
            const int i = s / 11, q = s % 11;
            float4 m4 = *reinterpret_cast<float4*>(&sM[i][q * 4]);
            const float rs = srs[i];
            m4.x *= rs; m4.y *= rs; m4.z *= rs; m4.w *= rs;
            *reinterpret_cast<float4*>(&sM[i][q * 4]) = m4;
            const float4 l4  = *reinterpret_cast<const float4*>(&sL[i][q * 4]);
            const float4 t24 = *reinterpret_cast<const float4*>(&sT2[i][q * 4]);
            const float4 t34 = *reinterpret_cast<const float4*>(&sT3[i][q * 4]);
            float4 w;
            w.x = fmaf(a1, l4.x, fmaf(a2, t24.x, a3 * t34.x));
            w.y = fmaf(a1, l4.y, fmaf(a2, t24.y, a3 * t34.y));
            w.z = fmaf(a1, l4.z, fmaf(a2, t24.z, a3 * t34.z));
            w.w = fmaf(a1, l4.w, fmaf(a2, t24.w, a3 * t34.w));
            w.x = (w.x < 1e-4f) ? 0.f : w.x;  w.y = (w.y < 1e-4f) ? 0.f : w.y;
            w.z = (w.z < 1e-4f) ? 0.f : w.z;  w.w = (w.w < 1e-4f) ? 0.f : w.w;
            *reinterpret_cast<float4*>(&sG[i][q * 4]) = w;
        }
        __syncthreads();
        if (tid < NN) {
            float s = 0.f;
            #pragma unroll
            for (int q = 0; q < 11; ++q) {
                const float4 w4 = *reinterpret_cast<const float4*>(&sG[tid][q * 4]);
                s += fabsf(w4.x) + fabsf(w4.y) + fabsf(w4.z) + fabsf(w4.w);
            }
            sdeg[tid] = gk[tid] / fmaxf(s, 1e-12f);
        }
        __syncthreads();
        for (int s = tid; s < NN * 11; s += WT) {
            const int j = s / 11, q = s % 11;
            float4 w4 = *reinterpret_cast<float4*>(&sG[j][q * 4]);
            const float rs = sdeg[j];
            w4.x *= rs; w4.y *= rs; w4.z *= rs; w4.w *= rs;
            *reinterpret_cast<float4*>(&sG[j][q * 4]) = w4;
        }
        __syncthreads();
    }
    lds_mm(sM, sG, sL, 1.0f, nullptr, tid);   // M = Wn @ diag(gk) Win
    __syncthreads();
    float* dst = MT + (size_t)b * NN * NN;
    for (int e = tid; e < NN * NN; e += WT) {
        const int j = e / NN, i = e % NN;
        dst[e] = sL[i][j];
    }
}

// ---------------------------------------------------------------------------
// Prep: weights -> split k-major Bint (W2 for gemm3) AND single-bf16
// k-major Bsng (gW, W1 for the fused kernel). Also coff = exp(lsv).
// ---------------------------------------------------------------------------
__global__ __launch_bounds__(256) void k_splitB(const float* __restrict__ gW,
                                                const float* __restrict__ W1,
                                                const float* __restrict__ W2,
                                                const float* __restrict__ lsv,
                                                unsigned short* __restrict__ Bint,
                                                unsigned short* __restrict__ Bsng,
                                                float* __restrict__ coff)
{
    const int t = blockIdx.x * 256 + threadIdx.x;
    if (t < NN * DD) coff[t] = expf(lsv[t]);
    if (t >= 3 * DP * DP) return;
    const int w = t / (DP * DP);
    const int r = t % (DP * DP);
    const int n = r / DP, k = r % DP;
    const float* src = (w == 0) ? gW : ((w == 1) ? W1 : W2);
    const float v = (n < DD && k < DD) ? src[k * DD + n] : 0.0f;
    store_split_km(Bint + (size_t)w * WBE, DP, n, k, v);
    if (w < 2) {
        Bsng[(size_t)w * WBS + ((long long)(k >> 5) * DP + n) * 32 +
             (((k & 31) >> 3) << 3) + (k & 7)] = f2bf(v);
    }
}

// ---------------------------------------------------------------------------
// K2 v9 (MFMA): Y = M @ X per sample -> single-bf16 k-major planes.
// (r24/r26 proven version, reverted from r28's half-staging regression)
// ---------------------------------------------------------------------------
__global__ __launch_bounds__(256, 2) void k_wavX(const float* __restrict__ MT,
                                                 const float* __restrict__ X,
                                                 unsigned short* __restrict__ Yint)
{
    constexpr int XJ  = 68;                    // j-stride (136B rows: 2-way banks)
    constexpr int YST = 296;                   // sYb col stride
    __shared__ __align__(16) unsigned short sXT[288 * XJ];  // 39168 B
    __shared__ __align__(16) unsigned short sMm[48 * XJ];   //  6528 B
    __shared__ __align__(16) unsigned short sYb[NN * YST];  // 24272 B
    const int b   = blockIdx.x;
    const int tid = threadIdx.x;
    const int lane = tid & 63, w = tid >> 6;
    const int lr = lane & 15;
    const int hi8 = (lane >> 4) * 8;

    // zero-fill (pads must be 0; uninitialized LDS could be NaN-pattern)
    const ushort8 z8 = {0, 0, 0, 0, 0, 0, 0, 0};
    for (int e = tid; e < (288 * XJ) / 8; e += 256)
        *reinterpret_cast<ushort8*>(&sXT[e * 8]) = z8;
    for (int e = tid; e < (48 * XJ) / 8; e += 256)
        *reinterpret_cast<ushort8*>(&sMm[e * 8]) = z8;
    __syncthreads();

    // stage X^T: sXT[c][j] = bf16(X[b][j][c]); coalesced f32 reads
    const float* __restrict__ Xb = X + (size_t)b * NN * DD;
    for (int e = tid; e < NN * DD; e += 256) {
        const int j = e / DD, c = e % DD;
        sXT[c * XJ + j] = f2bf(Xb[e]);
    }
    // stage M: sMm[i][j] = bf16(M[i][j]) = bf16(MT[b][j*41+i]); coalesced
    const float* __restrict__ Mb = MT + (size_t)b * NN * NN;
    for (int e = tid; e < NN * NN; e += 256) {
        const int j = e / NN, i = e % NN;
        sMm[i * XJ + j] = f2bf(Mb[e]);
    }
    __syncthreads();

    // MFMA: 3 m-tiles x 18 n-tiles of 16x16, K = 64 (2 steps of 32)
    for (int t = w; t < 54; t += 4) {
        const int mt = t / 18, nt = t % 18;
        f32x4 acc = (f32x4){0.f, 0.f, 0.f, 0.f};
        #pragma unroll
        for (int ks = 0; ks < 2; ++ks) {
            const short8 a = *reinterpret_cast<const short8*>(
                &sMm[(mt * 16 + lr) * XJ + ks * 32 + hi8]);
            const short8 bf = *reinterpret_cast<const short8*>(
                &sXT[(nt * 16 + lr) * XJ + ks * 32 + hi8]);
            acc = __builtin_amdgcn_mfma_f32_16x16x32_bf16(a, bf, acc, 0, 0, 0);
        }
        const int row0 = mt * 16 + (lane >> 4) * 4;
        const int col  = nt * 16 + lr;
        #pragma unroll
        for (int rr = 0; rr < 4; ++rr) {
            const int row = row0 + rr;
            if (row < NN) sYb[row * YST + col] = f2bf(acc[rr]);
        }
    }
    __syncthreads();

    // repack to Yint plane layout with 16B stores
    for (int t = tid; t < NN * 36; t += 256) {
        const int i = t / 36, c8 = t % 36;
        const ushort8 hv = *reinterpret_cast<const ushort8*>(&sYb[i * YST + c8 * 8]);
        const long long r = (long long)b * NN + i;
        const int p = c8 >> 3;                           // plane (64k)
        const int chunk = ((c8 >> 2) & 1) * 4 + (c8 & 3);
        const int sw = (int)(r & 7);
        unsigned short* base = Yint + ((long long)p * MROWS + r) * 64;
        *reinterpret_cast<ushort8*>(base + ((chunk ^ sw) << 3)) = hv;
    }
}

// ---------------------------------------------------------------------------
__device__ __forceinline__ void async16(const unsigned short* __restrict__ g,
                                        unsigned short* l)
{
    __builtin_amdgcn_global_load_lds(
        (const __attribute__((address_space(1))) unsigned int*)g,
        (__attribute__((address_space(3))) unsigned int*)l, 16, 0, 0);
}

// ---------------------------------------------------------------------------
// K3 v11: FUSED GEMM1+GEMM2+NODE-MEAN, atomic-free hot path (r26 winner).
// ---------------------------------------------------------------------------
__global__ __launch_bounds__(512, 2) void k_fused(
    const unsigned short* __restrict__ Aint,   // Y, single k-major planes
    const unsigned short* __restrict__ Bs0,    // gW single k-major
    const unsigned short* __restrict__ Bs1,    // W1 single k-major
    const float* __restrict__ coff,
    const float* __restrict__ b1,
    float* __restrict__ seqsum)                // [BB][DP] f32, pre-zeroed
{
    __shared__ __align__(16) unsigned short sS[256 * SROW];     // 156 KB
    const int tid  = threadIdx.x;
    const int lane = tid & 63, w = tid >> 6;    // 8 waves
    const int wr = w >> 1, wc = w & 1;          // wr 0..3 (64-row groups)
    const int lr = lane & 15, cb = lane >> 4;
    const int sw = lr & 7;

    const int nwg = gridDim.x, orig = blockIdx.x;
    const int q = nwg >> 3, r = nwg & 7;
    const int xcd = orig & 7, loc = orig >> 3;
    const int bid = (xcd < r ? xcd * (q + 1) : r * (q + 1) + (xcd - r) * q) + loc;
    const long long row0 = (long long)bid * 256;

    const unsigned short* __restrict__ b0p = Bs0 + (size_t)(wc * 144 + lr) * 32 + cb * 8;
    const unsigned short* __restrict__ b1p = Bs1 + (size_t)(wc * 144 + lr) * 32 + cb * 8;

    f32x4 acc[4][9];
    #pragma unroll
    for (int mf = 0; mf < 4; ++mf)
        #pragma unroll
        for (int nf = 0; nf < 9; ++nf)
            acc[mf][nf] = (f32x4){0.f, 0.f, 0.f, 0.f};

    // ---------------- phase 1: acc = Y @ gW  (NO barriers) ----------------
    for (int t = 0; t < 9; ++t) {
        const int p  = t >> 1;
        const int hc = (t & 1) * 4 + cb;
        const long long abase = ((long long)p * MROWS + row0) * 64 + ((hc ^ sw) << 3);
        short8 a[4];
        #pragma unroll
        for (int mf = 0; mf < 4; ++mf)
            a[mf] = *reinterpret_cast<const short8*>(
                Aint + abase + (long long)(wr * 64 + mf * 16 + lr) * 64);
        const long long toff = (long long)t * DP * 32;
        #pragma unroll
        for (int nf = 0; nf < 9; ++nf) {
            const short8 bh = *reinterpret_cast<const short8*>(b0p + toff + (long long)nf * 512);
            #pragma unroll
            for (int mf = 0; mf < 4; ++mf)
                acc[mf][nf] = __builtin_amdgcn_mfma_f32_16x16x32_bf16(a[mf], bh, acc[mf][nf], 0, 0, 0);
        }
    }

    // epilogue 1: S = coff*relu(acc) -> sS (pad cols get coff 0 -> S=0)
    #pragma unroll
    for (int mf = 0; mf < 4; ++mf) {
        const int mb = wr * 64 + mf * 16 + ((lane >> 4) * 4);
        #pragma unroll
        for (int nf = 0; nf < 9; ++nf) {
            const int col = wc * 144 + nf * 16 + lr;
            #pragma unroll
            for (int rr = 0; rr < 4; ++rr) {
                const int m = mb + rr;
                float v = fmaxf(acc[mf][nf][rr], 0.f);
                const float cf = (col < DD) ? coff[((unsigned)(row0 + m) % 41u) * DD + col] : 0.0f;
                sS[m * SROW + col] = f2bf(v * cf);
                acc[mf][nf][rr] = 0.f;
            }
        }
    }
    __syncthreads();   // S complete before cross-wave reads

    // ---------------- phase 2: acc = S @ W1 (single A from LDS, single B) --
    for (int t = 0; t < 9; ++t) {
        short8 ah[4];
        #pragma unroll
        for (int mf = 0; mf < 4; ++mf) {
            const int m = wr * 64 + mf * 16 + lr;
            ah[mf] = *reinterpret_cast<const short8*>(&sS[m * SROW + t * 32 + cb * 8]);
        }
        const long long toff = (long long)t * DP * 32;
        #pragma unroll
        for (int nf = 0; nf < 9; ++nf) {
            const short8 bh = *reinterpret_cast<const short8*>(b1p + toff + (long long)nf * 512);
            #pragma unroll
            for (int mf = 0; mf < 4; ++mf)
                acc[mf][nf] = __builtin_amdgcn_mfma_f32_16x16x32_bf16(ah[mf], bh, acc[mf][nf], 0, 0, 0);
        }
    }
    __syncthreads();   // all phase-2 sS reads complete before overwrite

    // epilogue 2a: P2 values (bf16) -> sS, own rows only (no hazards)
    #pragma unroll
    for (int mf = 0; mf < 4; ++mf) {
        const int mb = wr * 64 + mf * 16 + ((lane >> 4) * 4);
        #pragma unroll
        for (int nf = 0; nf < 9; ++nf) {
            const int col = wc * 144 + nf * 16 + lr;
            const float bv = (col < DD) ? b1[col] : 0.0f;
            #pragma unroll
            for (int rr = 0; rr < 4; ++rr) {
                const float v = fmaxf(acc[mf][nf][rr] + bv, 0.f);
                sS[(mb + rr) * SROW + col] = f2bf(v);
            }
        }
    }
    __syncthreads();

    // epilogue 2b: cooperative node-sum, then one global atomicAdd each
    const long long b0 = row0 / 41;
    for (int e = tid; e < 8 * DP; e += 512) {
        const int ls = e / DP, col = e % DP;
        const long long bsm = b0 + ls;
        if (bsm >= BB) continue;
        const long long gr0 = bsm * 41, gr1 = gr0 + 41;
        const int m0 = (int)((gr0 > row0 ? gr0 : row0) - row0);
        const long long hi = (gr1 < row0 + 256 ? gr1 : row0 + 256);
        const int m1 = (int)(hi - row0);
        if (m0 >= m1) continue;
        float s = 0.f;
        for (int m = m0; m < m1; ++m) s += bf2f(sS[m * SROW + col]);
        atomicAdd(&seqsum[bsm * DP + col], s);
    }
}

// ---------------------------------------------------------------------------
// K5: seqsum/41 -> split k-major MPint (BB rows).
// ---------------------------------------------------------------------------
__global__ __launch_bounds__(320) void k_mp(const float* __restrict__ seqsum,
                                            unsigned short* __restrict__ MPint)
{
    const int b = blockIdx.x;
    const int c = threadIdx.x;
    if (c >= DP) return;
    store_split_km(MPint, BB, b, c, seqsum[(size_t)b * DP + c] * (1.0f / 41.0f));
}

// ---------------------------------------------------------------------------
// K6: GEMM3 (small): seq = mean @ W2 + b2 (split path, unchanged).
// ---------------------------------------------------------------------------
__global__ __launch_bounds__(256, 2) void k_gemm3(
    const unsigned short* __restrict__ Aint,   // MPint, BB rows (split)
    const unsigned short* __restrict__ Bm,     // W2 split k-major
    const float* __restrict__ bias,
    float* __restrict__ outF)
{
    __shared__ __align__(16) unsigned short As2[2][128 * 64];
    const int tid  = threadIdx.x;
    const int lane = tid & 63, w = tid >> 6;
    const int wr = w >> 1, wc = w & 1;
    const int lr = lane & 15, cb = lane >> 4;
    const int sw = lr & 7;
    const long long row0 = (long long)blockIdx.x * 128;

    const size_t brow = (size_t)(wc * 144 + lr) * 64;
    const unsigned short* __restrict__ bhp = Bm + brow + ((cb ^ sw) << 3);
    const unsigned short* __restrict__ blp = Bm + brow + (((cb + 4) ^ sw) << 3);

    f32x4 acc[4][9];
    #pragma unroll
    for (int mf = 0; mf < 4; ++mf)
        #pragma unroll
        for (int nf = 0; nf < 9; ++nf)
            acc[mf][nf] = (f32x4){0.f, 0.f, 0.f, 0.f};

    auto stageA = [&](unsigned short* dst, int kt32) {
        const unsigned short* src = Aint + ((long long)kt32 * BB + row0) * 64;
        #pragma unroll
        for (int i = 0; i < 4; ++i) {
            const int cid = tid + i * 256;
            async16(src + (long long)cid * 8, dst + cid * 8);
        }
    };

    stageA(As2[0], 0);
    for (int t = 0; t < 9; ++t) {
        __syncthreads();
        if (t < 8) stageA(As2[(t + 1) & 1], t + 1);
        const unsigned short* As = As2[t & 1];
        short8 ah[4], al[4];
        #pragma unroll
        for (int mf = 0; mf < 4; ++mf) {
            const int m = wr * 64 + mf * 16 + lr;
            ah[mf] = *reinterpret_cast<const short8*>(&As[m * 64 + ((cb ^ sw) << 3)]);
            al[mf] = *reinterpret_cast<const short8*>(&As[m * 64 + (((cb + 4) ^ sw) << 3)]);
        }
        const long long toff = (long long)t * DP * 64;
        #pragma unroll
        for (int nf = 0; nf < 9; ++nf) {
            const long long d = toff + (long long)nf * 1024;
            const short8 bh = *reinterpret_cast<const short8*>(bhp + d);
            const short8 bl = *reinterpret_cast<const short8*>(blp + d);
            #pragma unroll
            for (int mf = 0; mf < 4; ++mf) {
                acc[mf][nf] = __builtin_amdgcn_mfma_f32_16x16x32_bf16(ah[mf], bh, acc[mf][nf], 0, 0, 0);
                acc[mf][nf] = __builtin_amdgcn_mfma_f32_16x16x32_bf16(al[mf], bh, acc[mf][nf], 0, 0, 0);
                acc[mf][nf] = __builtin_amdgcn_mfma_f32_16x16x32_bf16(ah[mf], bl, acc[mf][nf], 0, 0, 0);
            }
        }
    }

    #pragma unroll
    for (int mf = 0; mf < 4; ++mf) {
        const long long rb = row0 + wr * 64 + mf * 16 + ((lane >> 4) * 4);
        #pragma unroll
        for (int nf = 0; nf < 9; ++nf) {
            const int col = wc * 144 + nf * 16 + lr;
            const float bv = (col < DD) ? bias[col] : 0.0f;
            #pragma unroll
            for (int rr = 0; rr < 4; ++rr)
                outF[(rb + rr) * DP + col] = acc[mf][nf][rr] + bv;
        }
    }
}

// ---------------------------------------------------------------------------
__global__ __launch_bounds__(256) void k_stats(const float* __restrict__ seq, float* __restrict__ stats)
{
    __shared__ float s1[256], s2[256];
    const int d = blockIdx.x;
    float a = 0.f, q = 0.f;
    for (int b = threadIdx.x; b < BB; b += 256) {
        float v = seq[(size_t)b * DP + d];
        a += v; q = fmaf(v, v, q);
    }
    s1[threadIdx.x] = a; s2[threadIdx.x] = q;
    __syncthreads();
    for (int o = 128; o > 0; o >>= 1) {
        if (threadIdx.x < o) { s1[threadIdx.x] += s1[threadIdx.x + o]; s2[threadIdx.x] += s2[threadIdx.x + o]; }
        __syncthreads();
    }
    if (threadIdx.x == 0) {
        float m = s1[0] * (1.0f / BB);
        float v = s2[0] * (1.0f / BB) - m * m;
        stats[d]      = m;
        stats[DD + d] = 1.0f / sqrtf(v + 1e-5f);
    }
}

__global__ __launch_bounds__(256) void k_bn(const float* __restrict__ seq, const float* __restrict__ stats,
                                            const float* __restrict__ g, const float* __restrict__ bt,
                                            float* __restrict__ out)
{
    const long long idx = (long long)blockIdx.x * 256 + threadIdx.x;
    if (idx < (long long)BB * DD) {
        const int d = (int)(idx % DD);
        const long long b = idx / DD;
        out[idx] = (seq[b * DP + d] - stats[d]) * stats[DD + d] * g[d] + bt[d];
    }
}

// ---------------------------------------------------------------------------
extern "C" void kernel_launch(void* const* d_in, const int* in_sizes, int n_in,
                              void* d_out, int out_size, void* d_ws, size_t ws_size,
                              hipStream_t stream)
{
    const float* G   = (const float*)d_in[0];
    const float* X   = (const float*)d_in[1];
    const float* gk  = (const float*)d_in[2];
    const float* gW  = (const float*)d_in[3];
    const float* lsv = (const float*)d_in[4];
    const float* W1  = (const float*)d_in[5];
    const float* b1  = (const float*)d_in[6];
    const float* W2  = (const float*)d_in[7];
    const float* b2  = (const float*)d_in[8];
    const float* gam = (const float*)d_in[9];
    const float* bet = (const float*)d_in[10];

    char* p = (char*)d_ws;
    auto alloc = [&](size_t bytes) { void* r = (void*)p; p += (bytes + 255) & ~(size_t)255; return r; };
    float*          MT     = (float*)alloc((size_t)BB * NN * NN * 4);          // 27.5 MB
    unsigned short* Yint   = (unsigned short*)alloc((size_t)NPL * MROWS * 64 * 2); // 107.5 MB
    unsigned short* Bint   = (unsigned short*)alloc((size_t)3 * WBE * 2);      // 1 MB
    unsigned short* Bsng   = (unsigned short*)alloc((size_t)2 * WBS * 2);      // 0.33 MB
    unsigned short* MPint  = (unsigned short*)alloc((size_t)BB * 576 * 2);     // 4.7 MB
    float*          coff   = (float*)alloc((size_t)NN * DD * 4);
    float*          seqsum = (float*)alloc((size_t)BB * DP * 4);               // 4.7 MB
    float*          seqF   = (float*)alloc((size_t)BB * DP * 4);
    float*          stats  = (float*)alloc(2 * DD * 4);

    hipMemsetAsync(seqsum, 0, (size_t)BB * DP * 4, stream);

    k_wavelet<<<BB, WT, 0, stream>>>(G, gk, MT);
    k_splitB<<<(3 * DP * DP + 255) / 256, 256, 0, stream>>>(gW, W1, W2, lsv, Bint, Bsng, coff);
    k_wavX<<<BB, 256, 0, stream>>>(MT, X, Yint);

    // fused: node-sum of relu((coff*relu((M@X)@gW)) @ W1 + b1) -> seqsum
    k_fused<<<(unsigned)(MROWS / 256), 512, 0, stream>>>(Yint, Bsng, Bsng + WBS,
                                                         coff, b1, seqsum);
    // mean -> split layout for gemm3
    k_mp<<<BB, 320, 0, stream>>>(seqsum, MPint);
    // GEMM3: seq = mean @ W2 + b2
    k_gemm3<<<BB / 128, 256, 0, stream>>>(MPint, Bint + 2 * WBE, b2, seqF);
    k_stats<<<DD, 256, 0, stream>>>(seqF, stats);
    k_bn<<<(unsigned)(((long long)BB * DD + 255) / 256), 256, 0, stream>>>(seqF, stats, gam, bet, (float*)d_out);
}